// Round 8
// baseline (1135.471 us; speedup 1.0000x reference)
//
#include <hip/hip_runtime.h>
#include <hip/hip_bf16.h>
#include <math.h>

#define N_NODES 50000
#define N_EDGES 800000
#define N_GRAPHS 64
#define E2_TOTAL (N_EDGES + N_NODES)

typedef unsigned short u16;
typedef __attribute__((ext_vector_type(8))) short s16x8;
typedef __attribute__((ext_vector_type(4))) float f32x4;

__device__ __forceinline__ u16 f2bf(float f) {
    unsigned u = __float_as_uint(f);
    u += 0x7fffu + ((u >> 16) & 1u);   // round-to-nearest-even
    return (u16)(u >> 16);
}
__device__ __forceinline__ void unpack2(unsigned v, float& a, float& b) {
    a = __uint_as_float(v << 16);
    b = __uint_as_float(v & 0xffff0000u);
}
__device__ __forceinline__ unsigned pack2(float a, float b) {
    return (unsigned)f2bf(a) | ((unsigned)f2bf(b) << 16);
}

// ---------------------------------------------------------------- CSR build

__global__ __launch_bounds__(256) void deg_kernel(const int* __restrict__ ei,
                                                  const float* __restrict__ eattr,
                                                  int* __restrict__ deg,
                                                  float* __restrict__ asum, int E) {
    int e = blockIdx.x * 256 + threadIdx.x;
    if (e >= E) return;
    int dst = ei[E + e];
    atomicAdd(&deg[dst], 1);
    atomicAdd(&asum[dst * 3 + 0], eattr[e * 3 + 0]);
    atomicAdd(&asum[dst * 3 + 1], eattr[e * 3 + 1]);
    atomicAdd(&asum[dst * 3 + 2], eattr[e * 3 + 2]);
}

// exclusive scan of (deg+1); writes rowptr AND cursor
__global__ __launch_bounds__(1024) void scan_kernel(const int* __restrict__ deg,
                                                    int* __restrict__ rowptr,
                                                    int* __restrict__ cursor, int N) {
    __shared__ int wsum[16];
    __shared__ int carry_s;
    int tid = threadIdx.x, lane = tid & 63, wid = tid >> 6;
    if (tid == 0) carry_s = 0;
    __syncthreads();
    for (int base = 0; base < N; base += 4096) {
        int i0 = base + tid * 4;
        int d0 = (i0 + 0 < N) ? deg[i0 + 0] + 1 : 0;
        int d1 = (i0 + 1 < N) ? deg[i0 + 1] + 1 : 0;
        int d2 = (i0 + 2 < N) ? deg[i0 + 2] + 1 : 0;
        int d3 = (i0 + 3 < N) ? deg[i0 + 3] + 1 : 0;
        int v = d0 + d1 + d2 + d3;
        int x = v;
        #pragma unroll
        for (int off = 1; off < 64; off <<= 1) {
            int t = __shfl_up(x, off);
            if (lane >= off) x += t;
        }
        if (lane == 63) wsum[wid] = x;
        __syncthreads();
        if (wid == 0) {
            int y = (lane < 16) ? wsum[lane] : 0;
            #pragma unroll
            for (int off = 1; off < 16; off <<= 1) {
                int t = __shfl_up(y, off);
                if (lane >= off) y += t;
            }
            if (lane < 16) wsum[lane] = y;
        }
        __syncthreads();
        int woff = (wid > 0) ? wsum[wid - 1] : 0;
        int excl = carry_s + woff + x - v;
        if (i0 + 0 < N) { rowptr[i0 + 0] = excl;                cursor[i0 + 0] = excl; }
        if (i0 + 1 < N) { rowptr[i0 + 1] = excl + d0;           cursor[i0 + 1] = excl + d0; }
        if (i0 + 2 < N) { rowptr[i0 + 2] = excl + d0 + d1;      cursor[i0 + 2] = excl + d0 + d1; }
        if (i0 + 3 < N) { rowptr[i0 + 3] = excl + d0 + d1 + d2; cursor[i0 + 3] = excl + d0 + d1 + d2; }
        __syncthreads();
        if (tid == 1023) carry_s += wsum[15];
        __syncthreads();
    }
    if (threadIdx.x == 0) rowptr[N] = carry_s;
}

// CSR fill: meta[pos] = {ea0, ea1, ea2, src}; self-loop attr = asum/deg inline
__global__ __launch_bounds__(256) void fill_kernel(const int* __restrict__ ei,
                                                   const float* __restrict__ eattr,
                                                   const float* __restrict__ asum,
                                                   const int* __restrict__ deg,
                                                   int* __restrict__ cursor,
                                                   float4* __restrict__ meta,
                                                   int E, int E2) {
    int e = blockIdx.x * 256 + threadIdx.x;
    if (e >= E2) return;
    int src, dst;
    float a0, a1, a2;
    if (e < E) {
        src = ei[e]; dst = ei[E + e];
        a0 = eattr[(size_t)e * 3 + 0];
        a1 = eattr[(size_t)e * 3 + 1];
        a2 = eattr[(size_t)e * 3 + 2];
    } else {
        src = e - E; dst = src;
        float inv = 1.0f / (float)max(deg[dst], 1);
        a0 = asum[(size_t)dst * 3 + 0] * inv;
        a1 = asum[(size_t)dst * 3 + 1] * inv;
        a2 = asum[(size_t)dst * 3 + 2] * inv;
    }
    int pos = atomicAdd(&cursor[dst], 1);
    meta[pos] = make_float4(a0, a1, a2, __int_as_float(src));
}

// ---------------------------------------------------------------- XR1 = x@Wr+br (din=8) -> bf16

__global__ __launch_bounds__(256) void xw8_kernel(const float* __restrict__ x,
                                                  const float* __restrict__ Wr,
                                                  const float* __restrict__ br,
                                                  u16* __restrict__ Xb, int N) {
    __shared__ float sW[8 * 512];
    __shared__ float sb[512];
    __shared__ float sx[64][8];
    int tid = threadIdx.x;
    int nb = blockIdx.x * 64;
    for (int i = tid; i < 8 * 512; i += 256) sW[i] = Wr[i];
    for (int i = tid; i < 512; i += 256) sb[i] = br[i];
    for (int i = tid; i < 64 * 8; i += 256) {
        int j = i >> 3, k = i & 7;
        int n = nb + j;
        sx[j][k] = (n < N) ? x[(size_t)n * 8 + k] : 0.f;
    }
    __syncthreads();
    for (int it = 0; it < 64; it++) {
        int i = tid + it * 256;
        int j = i >> 8, c2 = (i & 255) * 2;
        int n = nb + j;
        if (n < N) {
            float v0 = sb[c2], v1 = sb[c2 + 1];
            #pragma unroll
            for (int k = 0; k < 8; k++) {
                float xv = sx[j][k];
                v0 += xv * sW[k * 512 + c2];
                v1 += xv * sW[k * 512 + c2 + 1];
            }
            *reinterpret_cast<unsigned*>(Xb + (size_t)n * 512 + c2) = pack2(v0, v1);
        }
    }
}

// ---------------------------------------------------------------- W -> Wt bf16 transpose (dual via blockIdx.z)

__global__ __launch_bounds__(256) void wt_dual(const float* __restrict__ WL,
                                               const float* __restrict__ WR,
                                               u16* __restrict__ WtL,
                                               u16* __restrict__ WtR, int K, int M) {
    const float* W = blockIdx.z ? WR : WL;
    u16* Wt = blockIdx.z ? WtR : WtL;
    __shared__ u16 t[64][65];
    int kb = blockIdx.x * 64, mb = blockIdx.y * 64;
    int tid = threadIdx.x;
    for (int i = tid; i < 64 * 64; i += 256) {
        int k = i >> 6, m = i & 63;
        t[m][k] = f2bf(W[(size_t)(kb + k) * M + mb + m]);
    }
    __syncthreads();
    for (int i = tid; i < 64 * 64; i += 256) {
        int m = i >> 6, k = i & 63;
        Wt[(size_t)(mb + m) * K + kb + k] = t[m][k];
    }
}

// ---------------------------------------------------------------- MFMA GEMM (bf16), dual via blockIdx.z

__global__ __launch_bounds__(256) void gemm_dual(const u16* __restrict__ A,
                                                 const u16* __restrict__ BtL,
                                                 const u16* __restrict__ BtR,
                                                 const float* __restrict__ biasL,
                                                 const float* __restrict__ biasR,
                                                 u16* __restrict__ YL,
                                                 u16* __restrict__ YR,
                                                 int N, int K, int M) {
    const u16* Bt = blockIdx.z ? BtR : BtL;
    const float* bias = blockIdx.z ? biasR : biasL;
    u16* Y = blockIdx.z ? YR : YL;
    constexpr int BM = 128, BK = 64;
    __shared__ u16 As[BM][BK + 8];
    __shared__ u16 Bs[BM][BK + 8];
    int tid = threadIdx.x;
    int wid = tid >> 6, lane = tid & 63;
    int wm = (wid >> 1) * 64, wn = (wid & 1) * 64;
    int bm = blockIdx.x * BM, bn = blockIdx.y * BM;
    int l15 = lane & 15, l4 = lane >> 4;
    f32x4 acc[4][4] = {};
    int sr = tid >> 3;
    int sc = (tid & 7) * 8;

    for (int k0 = 0; k0 < K; k0 += BK) {
        #pragma unroll
        for (int p = 0; p < 4; p++) {
            int r = p * 32 + sr;
            int grow = bm + r;
            uint4 av = make_uint4(0, 0, 0, 0);
            if (grow < N)
                av = *reinterpret_cast<const uint4*>(A + (size_t)grow * K + k0 + sc);
            *reinterpret_cast<uint4*>(&As[r][sc]) = av;
            uint4 bv = *reinterpret_cast<const uint4*>(Bt + (size_t)(bn + r) * K + k0 + sc);
            *reinterpret_cast<uint4*>(&Bs[r][sc]) = bv;
        }
        __syncthreads();
        #pragma unroll
        for (int kk = 0; kk < 2; kk++) {
            int kof = kk * 32 + l4 * 8;
            s16x8 af[4], bfr[4];
            #pragma unroll
            for (int i = 0; i < 4; i++) {
                af[i]  = *reinterpret_cast<const s16x8*>(&As[wm + i * 16 + l15][kof]);
                bfr[i] = *reinterpret_cast<const s16x8*>(&Bs[wn + i * 16 + l15][kof]);
            }
            #pragma unroll
            for (int i = 0; i < 4; i++)
                #pragma unroll
                for (int j = 0; j < 4; j++)
                    acc[i][j] = __builtin_amdgcn_mfma_f32_16x16x32_bf16(
                        af[i], bfr[j], acc[i][j], 0, 0, 0);
        }
        __syncthreads();
    }
    #pragma unroll
    for (int i = 0; i < 4; i++) {
        #pragma unroll
        for (int j = 0; j < 4; j++) {
            int col = bn + wn + j * 16 + l15;
            float bv = bias[col];
            #pragma unroll
            for (int r = 0; r < 4; r++) {
                int row = bm + wm + i * 16 + l4 * 4 + r;
                if (row < N)
                    Y[(size_t)row * M + col] = f2bf(acc[i][j][r] + bv);
            }
        }
    }
}

// ---------------------------------------------------------------- wave-per-node GATv2
// SPLIT waves per node; scalar meta loads; REC: recompute xl from 8-dim x
// via SGPR loads + register Wl slice (layer 1); else gather bf16 XL rows.
// 2 edges/iter, 2-ahead prefetch, defer-max softmax, fused LN-stat buckets.

template <int HC, int SPLIT, bool F32OUT, bool REC>
__global__ __launch_bounds__(256) void attn_wave(
    const int* __restrict__ rowptr, const float4* __restrict__ meta,
    const u16* __restrict__ XLbf, const u16* __restrict__ XRbf,
    const float* __restrict__ We, const float* __restrict__ att,
    const float* __restrict__ bo, float* __restrict__ outf,
    u16* __restrict__ outb, double* __restrict__ sbuck,
    const float* __restrict__ x8, const float* __restrict__ Wl,
    const float* __restrict__ bl, int N) {
    constexpr int CW  = HC / SPLIT;   // channels per wave
    constexpr int CPL = CW / 64;      // 4 or 2
    constexpr int GS  = 128 / CPL;    // lanes per head group (32 or 64)
    int gw = blockIdx.x * 4 + (threadIdx.x >> 6);
    int lane = threadIdx.x & 63;
    int n = gw / SPLIT;
    int sub = gw - n * SPLIT;
    if (n >= N) return;
    int cb = sub * CW + lane * CPL;

    float xr[CPL], we0[CPL], we1[CPL], we2[CPL], sa[CPL], acc[CPL];
    #pragma unroll
    for (int i = 0; i < CPL; i++) {
        we0[i] = We[cb + i];
        we1[i] = We[HC + cb + i];
        we2[i] = We[2 * HC + cb + i];
        sa[i]  = att[cb + i];
        acc[i] = 0.f;
    }
    {
        const u16* p = XRbf + (size_t)n * HC + cb;
        if constexpr (CPL == 4) {
            uint2 r = *reinterpret_cast<const uint2*>(p);
            unpack2(r.x, xr[0], xr[1]); unpack2(r.y, xr[2], xr[3]);
        } else {
            unsigned r = *reinterpret_cast<const unsigned*>(p);
            unpack2(r, xr[0], xr[1]);
        }
    }

    int beg = __builtin_amdgcn_readfirstlane(rowptr[n]);
    int end = __builtin_amdgcn_readfirstlane(rowptr[n + 1]);
    int e1 = end - 1;
    float m = -INFINITY, l = 0.f;

    if constexpr (REC) {
        // register-resident Wl slice + bl
        float wl[8][CPL], blv[CPL];
        #pragma unroll
        for (int k = 0; k < 8; k++)
            #pragma unroll
            for (int i = 0; i < CPL; i++) wl[k][i] = Wl[k * HC + cb + i];
        #pragma unroll
        for (int i = 0; i < CPL; i++) blv[i] = bl[cb + i];

        auto ldx = [&](int src, float* xk) {
            const float4* xp = reinterpret_cast<const float4*>(x8 + (size_t)src * 8);
            float4 a = xp[0], b = xp[1];
            xk[0] = a.x; xk[1] = a.y; xk[2] = a.z; xk[3] = a.w;
            xk[4] = b.x; xk[5] = b.y; xk[6] = b.z; xk[7] = b.w;
        };

        float4 mdA = meta[beg];
        float4 mdB = meta[min(beg + 1, e1)];
        int sA = __builtin_amdgcn_readfirstlane(__float_as_int(mdA.w));
        int sB = __builtin_amdgcn_readfirstlane(__float_as_int(mdB.w));
        float xkA[8], xkB[8];
        ldx(sA, xkA); ldx(sB, xkB);

        for (int j = beg; j < end; j += 2) {
            float4 mdA_n = meta[min(j + 2, e1)];
            float4 mdB_n = meta[min(j + 3, e1)];
            int sAn = __builtin_amdgcn_readfirstlane(__float_as_int(mdA_n.w));
            int sBn = __builtin_amdgcn_readfirstlane(__float_as_int(mdB_n.w));
            float xkA_n[8], xkB_n[8];
            ldx(sAn, xkA_n); ldx(sBn, xkB_n);

            float xl0[CPL], xl1[CPL];
            #pragma unroll
            for (int i = 0; i < CPL; i++) {
                float a0 = blv[i], a1 = blv[i];
                #pragma unroll
                for (int k = 0; k < 8; k++) {
                    a0 = fmaf(xkA[k], wl[k][i], a0);
                    a1 = fmaf(xkB[k], wl[k][i], a1);
                }
                xl0[i] = a0; xl1[i] = a1;
            }
            float p0 = 0.f, p1 = 0.f;
            #pragma unroll
            for (int i = 0; i < CPL; i++) {
                float u0 = fmaf(mdA.x, we0[i],
                           fmaf(mdA.y, we1[i],
                           fmaf(mdA.z, we2[i], xl0[i] + xr[i])));
                float u1 = fmaf(mdB.x, we0[i],
                           fmaf(mdB.y, we1[i],
                           fmaf(mdB.z, we2[i], xl1[i] + xr[i])));
                p0 = fmaf(fmaxf(u0, 0.2f * u0), sa[i], p0);
                p1 = fmaf(fmaxf(u1, 0.2f * u1), sa[i], p1);
            }
            #pragma unroll
            for (int off = GS / 2; off >= 1; off >>= 1) {
                p0 += __shfl_xor(p0, off);
                p1 += __shfl_xor(p1, off);
            }
            if (j + 1 > e1) p1 = -INFINITY;
            float hi = fmaxf(p0, p1);
            if (__all(hi <= m + 8.f)) {
                float w0 = __expf(p0 - m), w1 = __expf(p1 - m);
                l += w0 + w1;
                #pragma unroll
                for (int i = 0; i < CPL; i++)
                    acc[i] = fmaf(w0, xl0[i], fmaf(w1, xl1[i], acc[i]));
            } else {
                float mn = fmaxf(m, hi);
                float sc = __expf(m - mn);
                float w0 = __expf(p0 - mn), w1 = __expf(p1 - mn);
                l = fmaf(l, sc, w0 + w1);
                #pragma unroll
                for (int i = 0; i < CPL; i++)
                    acc[i] = fmaf(acc[i], sc, fmaf(w0, xl0[i], w1 * xl1[i]));
                m = mn;
            }
            mdA = mdA_n; mdB = mdB_n;
            #pragma unroll
            for (int k = 0; k < 8; k++) { xkA[k] = xkA_n[k]; xkB[k] = xkB_n[k]; }
        }
    } else {
        auto ldxl = [&](int src) -> uint2 {
            const u16* p = XLbf + (size_t)src * HC + cb;
            if constexpr (CPL == 4) {
                return *reinterpret_cast<const uint2*>(p);
            } else {
                uint2 r; r.x = *reinterpret_cast<const unsigned*>(p); r.y = 0;
                return r;
            }
        };

        float4 mdA = meta[beg];
        float4 mdB = meta[min(beg + 1, e1)];
        int sA = __builtin_amdgcn_readfirstlane(__float_as_int(mdA.w));
        int sB = __builtin_amdgcn_readfirstlane(__float_as_int(mdB.w));
        uint2 rA = ldxl(sA), rB = ldxl(sB);

        for (int j = beg; j < end; j += 2) {
            float4 mdA_n = meta[min(j + 2, e1)];
            float4 mdB_n = meta[min(j + 3, e1)];
            int sAn = __builtin_amdgcn_readfirstlane(__float_as_int(mdA_n.w));
            int sBn = __builtin_amdgcn_readfirstlane(__float_as_int(mdB_n.w));
            uint2 rA_n = ldxl(sAn), rB_n = ldxl(sBn);

            float xl0[CPL], xl1[CPL];
            if constexpr (CPL == 4) {
                unpack2(rA.x, xl0[0], xl0[1]); unpack2(rA.y, xl0[2], xl0[3]);
                unpack2(rB.x, xl1[0], xl1[1]); unpack2(rB.y, xl1[2], xl1[3]);
            } else {
                unpack2(rA.x, xl0[0], xl0[1]);
                unpack2(rB.x, xl1[0], xl1[1]);
            }
            float p0 = 0.f, p1 = 0.f;
            #pragma unroll
            for (int i = 0; i < CPL; i++) {
                float u0 = fmaf(mdA.x, we0[i],
                           fmaf(mdA.y, we1[i],
                           fmaf(mdA.z, we2[i], xl0[i] + xr[i])));
                float u1 = fmaf(mdB.x, we0[i],
                           fmaf(mdB.y, we1[i],
                           fmaf(mdB.z, we2[i], xl1[i] + xr[i])));
                p0 = fmaf(fmaxf(u0, 0.2f * u0), sa[i], p0);
                p1 = fmaf(fmaxf(u1, 0.2f * u1), sa[i], p1);
            }
            #pragma unroll
            for (int off = GS / 2; off >= 1; off >>= 1) {
                p0 += __shfl_xor(p0, off);
                p1 += __shfl_xor(p1, off);
            }
            if (j + 1 > e1) p1 = -INFINITY;
            float hi = fmaxf(p0, p1);
            if (__all(hi <= m + 8.f)) {
                float w0 = __expf(p0 - m), w1 = __expf(p1 - m);
                l += w0 + w1;
                #pragma unroll
                for (int i = 0; i < CPL; i++)
                    acc[i] = fmaf(w0, xl0[i], fmaf(w1, xl1[i], acc[i]));
            } else {
                float mn = fmaxf(m, hi);
                float sc = __expf(m - mn);
                float w0 = __expf(p0 - mn), w1 = __expf(p1 - mn);
                l = fmaf(l, sc, w0 + w1);
                #pragma unroll
                for (int i = 0; i < CPL; i++)
                    acc[i] = fmaf(acc[i], sc, fmaf(w0, xl0[i], w1 * xl1[i]));
                m = mn;
            }
            mdA = mdA_n; mdB = mdB_n; rA = rA_n; rB = rB_n;
        }
    }

    float inv = 1.f / (l + 1e-16f);
    float o[CPL];
    float s = 0.f, s2 = 0.f;
    #pragma unroll
    for (int i = 0; i < CPL; i++) {
        o[i] = acc[i] * inv + bo[cb + i];
        s += o[i]; s2 += o[i] * o[i];
    }
    if constexpr (F32OUT) {
        float* q = outf + (size_t)n * HC + cb;
        if constexpr (CPL == 4) {
            *reinterpret_cast<float4*>(q) = make_float4(o[0], o[1], o[2], o[3]);
        } else {
            *reinterpret_cast<float2*>(q) = make_float2(o[0], o[1]);
        }
    } else {
        u16* q = outb + (size_t)n * HC + cb;
        if constexpr (CPL == 4) {
            *reinterpret_cast<uint2*>(q) =
                make_uint2(pack2(o[0], o[1]), pack2(o[2], o[3]));
        } else {
            *reinterpret_cast<unsigned*>(q) = pack2(o[0], o[1]);
        }
    }
    #pragma unroll
    for (int off = 32; off; off >>= 1) {
        s += __shfl_xor(s, off);
        s2 += __shfl_xor(s2, off);
    }
    if (lane == 0) {
        double* bk = sbuck + (size_t)(blockIdx.x & 511) * 2;
        atomicAdd(bk, (double)s);
        atomicAdd(bk + 1, (double)s2);
    }
}

// ---------------------------------------------------------------- bucket reduce helper (in-block)

__device__ __forceinline__ float2 reduce_buckets(const double* __restrict__ buck,
                                                 double count) {
    __shared__ float2 res;
    int t = threadIdx.x;
    double s  = buck[t * 2]     + buck[(t + 256) * 2];
    double s2 = buck[t * 2 + 1] + buck[(t + 256) * 2 + 1];
    #pragma unroll
    for (int off = 32; off; off >>= 1) {
        s += __shfl_xor(s, off);
        s2 += __shfl_xor(s2, off);
    }
    __shared__ double a[4], b[4];
    int wid = t >> 6, lane = t & 63;
    if (lane == 0) { a[wid] = s; b[wid] = s2; }
    __syncthreads();
    if (t == 0) {
        double S = a[0] + a[1] + a[2] + a[3];
        double S2 = b[0] + b[1] + b[2] + b[3];
        double mu = S / count;
        double var = S2 / count - mu * mu;
        float sd = (float)sqrt(var > 0.0 ? var : 0.0);
        res.x = (float)mu;
        res.y = 1.f / (sd + 1e-5f);
    }
    __syncthreads();
    return res;
}

// ---------------------------------------------------------------- LN apply + ELU (bf16 in-place, fused finalize)

__global__ __launch_bounds__(256) void ln_apply_elu_bf(u16* __restrict__ x,
                                                       const double* __restrict__ buck,
                                                       double count,
                                                       const float* __restrict__ w,
                                                       const float* __restrict__ b,
                                                       int F, size_t cnt) {
    float2 lp = reduce_buckets(buck, count);
    float muf = lp.x, rs = lp.y;
    size_t stride = (size_t)gridDim.x * 256 * 8;
    for (size_t i = ((size_t)blockIdx.x * 256 + threadIdx.x) * 8; i < cnt; i += stride) {
        uint4 v = *reinterpret_cast<const uint4*>(x + i);
        float f[8];
        unpack2(v.x, f[0], f[1]); unpack2(v.y, f[2], f[3]);
        unpack2(v.z, f[4], f[5]); unpack2(v.w, f[6], f[7]);
        int c = (int)(i & (size_t)(F - 1));
        #pragma unroll
        for (int k = 0; k < 8; k++) {
            float u = (f[k] - muf) * rs * w[c + k] + b[c + k];
            f[k] = u > 0.f ? u : expm1f(u);
        }
        uint4 o = make_uint4(pack2(f[0], f[1]), pack2(f[2], f[3]),
                             pack2(f[4], f[5]), pack2(f[6], f[7]));
        *reinterpret_cast<uint4*>(x + i) = o;
    }
}

// ---------------------------------------------------------------- pooling: fused LN finalize + LN+ELU + goff search

__global__ __launch_bounds__(256) void pool_ln(const float* __restrict__ h,
                                               const int* __restrict__ batch,
                                               const double* __restrict__ buck,
                                               double count,
                                               const float* __restrict__ lw,
                                               const float* __restrict__ lb,
                                               float* __restrict__ out, int N) {
    float2 lp = reduce_buckets(buck, count);
    __shared__ float sh[128], mh[128];
    int g = blockIdx.x;
    // binary search graph range (batch sorted)
    int s_ = 0, hi_ = N;
    while (s_ < hi_) { int mid = (s_ + hi_) >> 1; if (batch[mid] < g) s_ = mid + 1; else hi_ = mid; }
    int e_ = s_, hi2 = N;
    while (e_ < hi2) { int mid = (e_ + hi2) >> 1; if (batch[mid] < g + 1) e_ = mid + 1; else hi2 = mid; }
    int tid = threadIdx.x;
    int c = tid & 127, part = tid >> 7;
    float wc = lw[c] * lp.y, bc = lb[c];
    float sum = 0.f, mx = -INFINITY;
    for (int n = s_ + part; n < e_; n += 2) {
        float v = (h[(size_t)n * 128 + c] - lp.x) * wc + bc;
        v = v > 0.f ? v : expm1f(v);
        sum += v;
        mx = fmaxf(mx, v);
    }
    if (part == 1) { sh[c] = sum; mh[c] = mx; }
    __syncthreads();
    if (part == 0) {
        if (e_ - s_ > 1) { sum += sh[c]; mx = fmaxf(mx, mh[c]); }
        int cnt = e_ - s_;
        out[g * 256 + c] = cnt > 0 ? sum / (float)cnt : 0.f;
        out[g * 256 + 128 + c] = cnt > 0 ? mx : 0.f;
    }
}

// ---------------------------------------------------------------- launch

extern "C" void kernel_launch(void* const* d_in, const int* in_sizes, int n_in,
                              void* d_out, int out_size, void* d_ws, size_t ws_size,
                              hipStream_t stream) {
    const int N = N_NODES, E = N_EDGES, G = N_GRAPHS, E2 = E2_TOTAL;
    const float* x = (const float*)d_in[0];
    const int* ei = (const int*)d_in[1];
    const float* eattr = (const float*)d_in[2];
    const int* batch = (const int*)d_in[3];
    auto P = [&](int l, int k) { return (const float*)d_in[4 + l * 9 + k]; };
    // k: 0=Wl 1=bl 2=Wr 3=br 4=We 5=att 6=bo 7=lnw 8=lnb

    char* w = (char*)d_ws;
    size_t off = 0;
    auto alloc = [&](size_t bytes) -> void* {
        void* p = w + off;
        off += (bytes + 255) & ~(size_t)255;
        return p;
    };
    u16* Xa = (u16*)alloc((size_t)N * 512 * 2);      // XL (layers 2/3)
    u16* Xb = (u16*)alloc((size_t)N * 512 * 2);      // XR per layer
    u16* Xc = (u16*)alloc((size_t)N * 512 * 2);      // h per layer
    float* H3f = (float*)alloc((size_t)N * 128 * 4); // layer-3 attn out fp32
    float4* meta = (float4*)alloc((size_t)E2 * 16);  // CSR-ordered {ea, src}
    u16* WtL = (u16*)alloc((size_t)512 * 256 * 2);
    u16* WtR = (u16*)alloc((size_t)512 * 256 * 2);
    int* rowptr = (int*)alloc((size_t)(N + 1) * 4);
    int* cursor = (int*)alloc((size_t)N * 4);
    // zero-initialized region: [zs, ze)
    size_t zs = off;
    int* deg = (int*)alloc((size_t)N * 4);
    float* asum = (float*)alloc((size_t)N * 3 * 4);
    double* b1 = (double*)alloc(512 * 2 * 8);
    double* b2 = (double*)alloc(512 * 2 * 8);
    double* b3 = (double*)alloc(512 * 2 * 8);
    size_t ze = off;
    (void)ws_size; (void)n_in; (void)in_sizes; (void)out_size;

    hipMemsetAsync(w + zs, 0, ze - zs, stream);

    deg_kernel<<<(E + 255) / 256, 256, 0, stream>>>(ei, eattr, deg, asum, E);
    scan_kernel<<<1, 1024, 0, stream>>>(deg, rowptr, cursor, N);
    fill_kernel<<<(E2 + 255) / 256, 256, 0, stream>>>(ei, eattr, asum, deg, cursor,
                                                      meta, E, E2);

    // -------- layer 1 (din=8, H=4, HC=512): xl recomputed, 2 waves/node
    xw8_kernel<<<(N + 63) / 64, 256, 0, stream>>>(x, P(0, 2), P(0, 3), Xb, N);
    attn_wave<512, 2, false, true><<<(N * 2 + 3) / 4, 256, 0, stream>>>(
        rowptr, meta, nullptr, Xb, P(0, 4), P(0, 5), P(0, 6),
        nullptr, Xc, b1, x, P(0, 0), P(0, 1), N);
    ln_apply_elu_bf<<<1024, 256, 0, stream>>>(Xc, b1, (double)N * 512.0,
                                              P(0, 7), P(0, 8), 512, (size_t)N * 512);

    // -------- layer 2 (din=512, H=2, HC=256): 2 waves/node
    {
        dim3 tg(512 / 64, 256 / 64, 2);
        wt_dual<<<tg, 256, 0, stream>>>(P(1, 0), P(1, 2), WtL, WtR, 512, 256);
        dim3 gg((N + 127) / 128, 2, 2);
        gemm_dual<<<gg, 256, 0, stream>>>(Xc, WtL, WtR, P(1, 1), P(1, 3),
                                          Xa, Xb, N, 512, 256);
    }
    attn_wave<256, 2, false, false><<<(N * 2 + 3) / 4, 256, 0, stream>>>(
        rowptr, meta, Xa, Xb, P(1, 4), P(1, 5), P(1, 6),
        nullptr, Xc, b2, nullptr, nullptr, nullptr, N);
    ln_apply_elu_bf<<<1024, 256, 0, stream>>>(Xc, b2, (double)N * 256.0,
                                              P(1, 7), P(1, 8), 256, (size_t)N * 256);

    // -------- layer 3 (din=256, H=1, HC=128)
    {
        dim3 tg(256 / 64, 128 / 64, 2);
        wt_dual<<<tg, 256, 0, stream>>>(P(2, 0), P(2, 2), WtL, WtR, 256, 128);
        dim3 gg((N + 127) / 128, 1, 2);
        gemm_dual<<<gg, 256, 0, stream>>>(Xc, WtL, WtR, P(2, 1), P(2, 3),
                                          Xa, Xb, N, 256, 128);
    }
    attn_wave<128, 1, true, false><<<(N + 3) / 4, 256, 0, stream>>>(
        rowptr, meta, Xa, Xb, P(2, 4), P(2, 5), P(2, 6),
        H3f, nullptr, b3, nullptr, nullptr, nullptr, N);

    // -------- pooling (fused LN finalize + apply + goff search)
    pool_ln<<<G, 256, 0, stream>>>(H3f, batch, b3, (double)N * 128.0,
                                   P(2, 7), P(2, 8), (float*)d_out, N);
}

// Round 9
// 987.482 us; speedup vs baseline: 1.1499x; 1.1499x over previous
//
#include <hip/hip_runtime.h>
#include <hip/hip_bf16.h>
#include <math.h>

#define N_NODES 50000
#define N_EDGES 800000
#define N_GRAPHS 64
#define E2_TOTAL (N_EDGES + N_NODES)

typedef unsigned short u16;
typedef __attribute__((ext_vector_type(8))) short s16x8;
typedef __attribute__((ext_vector_type(4))) float f32x4;

__device__ __forceinline__ u16 f2bf(float f) {
    unsigned u = __float_as_uint(f);
    u += 0x7fffu + ((u >> 16) & 1u);   // round-to-nearest-even
    return (u16)(u >> 16);
}
__device__ __forceinline__ void unpack2(unsigned v, float& a, float& b) {
    a = __uint_as_float(v << 16);
    b = __uint_as_float(v & 0xffff0000u);
}
__device__ __forceinline__ unsigned pack2(float a, float b) {
    return (unsigned)f2bf(a) | ((unsigned)f2bf(b) << 16);
}

// ---------------------------------------------------------------- CSR build

__global__ __launch_bounds__(256) void deg_kernel(const int* __restrict__ ei,
                                                  const float* __restrict__ eattr,
                                                  int* __restrict__ deg,
                                                  float* __restrict__ asum, int E) {
    int e = blockIdx.x * 256 + threadIdx.x;
    if (e >= E) return;
    int dst = ei[E + e];
    atomicAdd(&deg[dst], 1);
    atomicAdd(&asum[dst * 3 + 0], eattr[e * 3 + 0]);
    atomicAdd(&asum[dst * 3 + 1], eattr[e * 3 + 1]);
    atomicAdd(&asum[dst * 3 + 2], eattr[e * 3 + 2]);
}

// exclusive scan of (deg+1); writes rowptr AND cursor
__global__ __launch_bounds__(1024) void scan_kernel(const int* __restrict__ deg,
                                                    int* __restrict__ rowptr,
                                                    int* __restrict__ cursor, int N) {
    __shared__ int wsum[16];
    __shared__ int carry_s;
    int tid = threadIdx.x, lane = tid & 63, wid = tid >> 6;
    if (tid == 0) carry_s = 0;
    __syncthreads();
    for (int base = 0; base < N; base += 4096) {
        int i0 = base + tid * 4;
        int d0 = (i0 + 0 < N) ? deg[i0 + 0] + 1 : 0;
        int d1 = (i0 + 1 < N) ? deg[i0 + 1] + 1 : 0;
        int d2 = (i0 + 2 < N) ? deg[i0 + 2] + 1 : 0;
        int d3 = (i0 + 3 < N) ? deg[i0 + 3] + 1 : 0;
        int v = d0 + d1 + d2 + d3;
        int x = v;
        #pragma unroll
        for (int off = 1; off < 64; off <<= 1) {
            int t = __shfl_up(x, off);
            if (lane >= off) x += t;
        }
        if (lane == 63) wsum[wid] = x;
        __syncthreads();
        if (wid == 0) {
            int y = (lane < 16) ? wsum[lane] : 0;
            #pragma unroll
            for (int off = 1; off < 16; off <<= 1) {
                int t = __shfl_up(y, off);
                if (lane >= off) y += t;
            }
            if (lane < 16) wsum[lane] = y;
        }
        __syncthreads();
        int woff = (wid > 0) ? wsum[wid - 1] : 0;
        int excl = carry_s + woff + x - v;
        if (i0 + 0 < N) { rowptr[i0 + 0] = excl;                cursor[i0 + 0] = excl; }
        if (i0 + 1 < N) { rowptr[i0 + 1] = excl + d0;           cursor[i0 + 1] = excl + d0; }
        if (i0 + 2 < N) { rowptr[i0 + 2] = excl + d0 + d1;      cursor[i0 + 2] = excl + d0 + d1; }
        if (i0 + 3 < N) { rowptr[i0 + 3] = excl + d0 + d1 + d2; cursor[i0 + 3] = excl + d0 + d1 + d2; }
        __syncthreads();
        if (tid == 1023) carry_s += wsum[15];
        __syncthreads();
    }
    if (threadIdx.x == 0) rowptr[N] = carry_s;
}

// CSR fill: meta[pos] = {ea0, ea1, ea2, src}; self-loop attr = asum/deg inline
__global__ __launch_bounds__(256) void fill_kernel(const int* __restrict__ ei,
                                                   const float* __restrict__ eattr,
                                                   const float* __restrict__ asum,
                                                   const int* __restrict__ deg,
                                                   int* __restrict__ cursor,
                                                   float4* __restrict__ meta,
                                                   int E, int E2) {
    int e = blockIdx.x * 256 + threadIdx.x;
    if (e >= E2) return;
    int src, dst;
    float a0, a1, a2;
    if (e < E) {
        src = ei[e]; dst = ei[E + e];
        a0 = eattr[(size_t)e * 3 + 0];
        a1 = eattr[(size_t)e * 3 + 1];
        a2 = eattr[(size_t)e * 3 + 2];
    } else {
        src = e - E; dst = src;
        float inv = 1.0f / (float)max(deg[dst], 1);
        a0 = asum[(size_t)dst * 3 + 0] * inv;
        a1 = asum[(size_t)dst * 3 + 1] * inv;
        a2 = asum[(size_t)dst * 3 + 2] * inv;
    }
    int pos = atomicAdd(&cursor[dst], 1);
    meta[pos] = make_float4(a0, a1, a2, __int_as_float(src));
}

// ---------------------------------------------------------------- X1 = x@W+b (din=8), both L and R -> bf16

__global__ __launch_bounds__(256) void xw8_dual(const float* __restrict__ x,
                                                const float* __restrict__ Wl,
                                                const float* __restrict__ bl,
                                                const float* __restrict__ Wr,
                                                const float* __restrict__ br,
                                                u16* __restrict__ Xa,
                                                u16* __restrict__ Xb, int N) {
    __shared__ float sWl[8 * 512], sWr[8 * 512];
    __shared__ float sbl[512], sbr[512];
    __shared__ float sx[64][8];
    int tid = threadIdx.x;
    int nb = blockIdx.x * 64;
    for (int i = tid; i < 8 * 512; i += 256) { sWl[i] = Wl[i]; sWr[i] = Wr[i]; }
    for (int i = tid; i < 512; i += 256) { sbl[i] = bl[i]; sbr[i] = br[i]; }
    for (int i = tid; i < 64 * 8; i += 256) {
        int j = i >> 3, k = i & 7;
        int n = nb + j;
        sx[j][k] = (n < N) ? x[(size_t)n * 8 + k] : 0.f;
    }
    __syncthreads();
    for (int it = 0; it < 64; it++) {
        int i = tid + it * 256;
        int j = i >> 8, c2 = (i & 255) * 2;
        int n = nb + j;
        if (n < N) {
            float l0 = sbl[c2], l1 = sbl[c2 + 1];
            float r0 = sbr[c2], r1 = sbr[c2 + 1];
            #pragma unroll
            for (int k = 0; k < 8; k++) {
                float xv = sx[j][k];
                l0 += xv * sWl[k * 512 + c2];
                l1 += xv * sWl[k * 512 + c2 + 1];
                r0 += xv * sWr[k * 512 + c2];
                r1 += xv * sWr[k * 512 + c2 + 1];
            }
            *reinterpret_cast<unsigned*>(Xa + (size_t)n * 512 + c2) = pack2(l0, l1);
            *reinterpret_cast<unsigned*>(Xb + (size_t)n * 512 + c2) = pack2(r0, r1);
        }
    }
}

// ---------------------------------------------------------------- bucket reduce helper (in-block, 256 thr)

__device__ __forceinline__ float2 reduce_buckets(const double* __restrict__ buck,
                                                 double count) {
    __shared__ float2 res;
    int t = threadIdx.x;
    double s  = buck[t * 2]     + buck[(t + 256) * 2];
    double s2 = buck[t * 2 + 1] + buck[(t + 256) * 2 + 1];
    #pragma unroll
    for (int off = 32; off; off >>= 1) {
        s += __shfl_xor(s, off);
        s2 += __shfl_xor(s2, off);
    }
    __shared__ double a[4], b[4];
    int wid = t >> 6, lane = t & 63;
    if (lane == 0) { a[wid] = s; b[wid] = s2; }
    __syncthreads();
    if (t == 0) {
        double S = a[0] + a[1] + a[2] + a[3];
        double S2 = b[0] + b[1] + b[2] + b[3];
        double mu = S / count;
        double var = S2 / count - mu * mu;
        float sd = (float)sqrt(var > 0.0 ? var : 0.0);
        res.x = (float)mu;
        res.y = 1.f / (sd + 1e-5f);
    }
    __syncthreads();
    return res;
}

// ---------------------------------------------------------------- W -> Wt bf16 transpose (dual via blockIdx.z)

__global__ __launch_bounds__(256) void wt_dual(const float* __restrict__ WL,
                                               const float* __restrict__ WR,
                                               u16* __restrict__ WtL,
                                               u16* __restrict__ WtR, int K, int M) {
    const float* W = blockIdx.z ? WR : WL;
    u16* Wt = blockIdx.z ? WtR : WtL;
    __shared__ u16 t[64][65];
    int kb = blockIdx.x * 64, mb = blockIdx.y * 64;
    int tid = threadIdx.x;
    for (int i = tid; i < 64 * 64; i += 256) {
        int k = i >> 6, m = i & 63;
        t[m][k] = f2bf(W[(size_t)(kb + k) * M + mb + m]);
    }
    __syncthreads();
    for (int i = tid; i < 64 * 64; i += 256) {
        int m = i >> 6, k = i & 63;
        Wt[(size_t)(mb + m) * K + kb + k] = t[m][k];
    }
}

// ---------------------------------------------------------------- MFMA GEMM (bf16), dual via blockIdx.z
// A-staging applies fused LayerNorm + ELU to the raw attention output:
// a' = elu((a - mu) * rs * lnw[c] + lnb[c]) ; stats from bucket array.

__global__ __launch_bounds__(256) void gemm_dual(const u16* __restrict__ A,
                                                 const u16* __restrict__ BtL,
                                                 const u16* __restrict__ BtR,
                                                 const float* __restrict__ biasL,
                                                 const float* __restrict__ biasR,
                                                 u16* __restrict__ YL,
                                                 u16* __restrict__ YR,
                                                 const double* __restrict__ buck,
                                                 double count,
                                                 const float* __restrict__ lnw,
                                                 const float* __restrict__ lnb,
                                                 int N, int K, int M) {
    const u16* Bt = blockIdx.z ? BtR : BtL;
    const float* bias = blockIdx.z ? biasR : biasL;
    u16* Y = blockIdx.z ? YR : YL;
    constexpr int BM = 128, BK = 64;
    __shared__ u16 As[BM][BK + 8];
    __shared__ u16 Bs[BM][BK + 8];
    __shared__ float sLw[512], sLb[512];
    float2 lp = reduce_buckets(buck, count);
    float muf = lp.x, rs = lp.y;
    int tid = threadIdx.x;
    for (int i = tid; i < K; i += 256) { sLw[i] = lnw[i] * rs; sLb[i] = lnb[i]; }
    int wid = tid >> 6, lane = tid & 63;
    int wm = (wid >> 1) * 64, wn = (wid & 1) * 64;
    int bm = blockIdx.x * BM, bn = blockIdx.y * BM;
    int l15 = lane & 15, l4 = lane >> 4;
    f32x4 acc[4][4] = {};
    int sr = tid >> 3;
    int sc = (tid & 7) * 8;
    __syncthreads();

    for (int k0 = 0; k0 < K; k0 += BK) {
        #pragma unroll
        for (int p = 0; p < 4; p++) {
            int r = p * 32 + sr;
            int grow = bm + r;
            uint4 av = make_uint4(0, 0, 0, 0);
            if (grow < N) {
                av = *reinterpret_cast<const uint4*>(A + (size_t)grow * K + k0 + sc);
                float f[8];
                unpack2(av.x, f[0], f[1]); unpack2(av.y, f[2], f[3]);
                unpack2(av.z, f[4], f[5]); unpack2(av.w, f[6], f[7]);
                #pragma unroll
                for (int q = 0; q < 8; q++) {
                    int c = k0 + sc + q;
                    float u = (f[q] - muf) * sLw[c] + sLb[c];
                    f[q] = u > 0.f ? u : expm1f(u);
                }
                av = make_uint4(pack2(f[0], f[1]), pack2(f[2], f[3]),
                                pack2(f[4], f[5]), pack2(f[6], f[7]));
            }
            *reinterpret_cast<uint4*>(&As[r][sc]) = av;
            uint4 bv = *reinterpret_cast<const uint4*>(Bt + (size_t)(bn + r) * K + k0 + sc);
            *reinterpret_cast<uint4*>(&Bs[r][sc]) = bv;
        }
        __syncthreads();
        #pragma unroll
        for (int kk = 0; kk < 2; kk++) {
            int kof = kk * 32 + l4 * 8;
            s16x8 af[4], bfr[4];
            #pragma unroll
            for (int i = 0; i < 4; i++) {
                af[i]  = *reinterpret_cast<const s16x8*>(&As[wm + i * 16 + l15][kof]);
                bfr[i] = *reinterpret_cast<const s16x8*>(&Bs[wn + i * 16 + l15][kof]);
            }
            #pragma unroll
            for (int i = 0; i < 4; i++)
                #pragma unroll
                for (int j = 0; j < 4; j++)
                    acc[i][j] = __builtin_amdgcn_mfma_f32_16x16x32_bf16(
                        af[i], bfr[j], acc[i][j], 0, 0, 0);
        }
        __syncthreads();
    }
    #pragma unroll
    for (int i = 0; i < 4; i++) {
        #pragma unroll
        for (int j = 0; j < 4; j++) {
            int col = bn + wn + j * 16 + l15;
            float bv = bias[col];
            #pragma unroll
            for (int r = 0; r < 4; r++) {
                int row = bm + wm + i * 16 + l4 * 4 + r;
                if (row < N)
                    Y[(size_t)row * M + col] = f2bf(acc[i][j][r] + bv);
            }
        }
    }
}

// ---------------------------------------------------------------- wave-per-node GATv2
// SPLIT waves per node; scalar meta loads; bf16 XL gather; 2 edges/iter with
// 2-ahead prefetch; defer-max online softmax; fused LN-stat bucket atomics.

template <int HC, int SPLIT, bool F32OUT>
__global__ __launch_bounds__(256) void attn_wave(
    const int* __restrict__ rowptr, const float4* __restrict__ meta,
    const u16* __restrict__ XLbf, const u16* __restrict__ XRbf,
    const float* __restrict__ We, const float* __restrict__ att,
    const float* __restrict__ bo, float* __restrict__ outf,
    u16* __restrict__ outb, double* __restrict__ sbuck, int N) {
    constexpr int CW  = HC / SPLIT;   // channels per wave
    constexpr int CPL = CW / 64;      // 4 or 2
    constexpr int GS  = 128 / CPL;    // lanes per head group (32 or 64)
    int gw = blockIdx.x * 4 + (threadIdx.x >> 6);
    int lane = threadIdx.x & 63;
    int n = gw / SPLIT;
    int sub = gw - n * SPLIT;
    if (n >= N) return;
    int cb = sub * CW + lane * CPL;

    float xr[CPL], we0[CPL], we1[CPL], we2[CPL], sa[CPL], acc[CPL];
    #pragma unroll
    for (int i = 0; i < CPL; i++) {
        we0[i] = We[cb + i];
        we1[i] = We[HC + cb + i];
        we2[i] = We[2 * HC + cb + i];
        sa[i]  = att[cb + i];
        acc[i] = 0.f;
    }
    {
        const u16* p = XRbf + (size_t)n * HC + cb;
        if constexpr (CPL == 4) {
            uint2 r = *reinterpret_cast<const uint2*>(p);
            unpack2(r.x, xr[0], xr[1]); unpack2(r.y, xr[2], xr[3]);
        } else {
            unsigned r = *reinterpret_cast<const unsigned*>(p);
            unpack2(r, xr[0], xr[1]);
        }
    }

    auto ldxl = [&](int src) -> uint2 {
        const u16* p = XLbf + (size_t)src * HC + cb;
        if constexpr (CPL == 4) {
            return *reinterpret_cast<const uint2*>(p);
        } else {
            uint2 r; r.x = *reinterpret_cast<const unsigned*>(p); r.y = 0;
            return r;
        }
    };

    int beg = __builtin_amdgcn_readfirstlane(rowptr[n]);
    int end = __builtin_amdgcn_readfirstlane(rowptr[n + 1]);
    int e1 = end - 1;
    float m = -INFINITY, l = 0.f;

    float4 mdA = meta[beg];
    float4 mdB = meta[min(beg + 1, e1)];
    int sA = __builtin_amdgcn_readfirstlane(__float_as_int(mdA.w));
    int sB = __builtin_amdgcn_readfirstlane(__float_as_int(mdB.w));
    uint2 rA = ldxl(sA), rB = ldxl(sB);

    for (int j = beg; j < end; j += 2) {
        float4 mdA_n = meta[min(j + 2, e1)];
        float4 mdB_n = meta[min(j + 3, e1)];
        int sAn = __builtin_amdgcn_readfirstlane(__float_as_int(mdA_n.w));
        int sBn = __builtin_amdgcn_readfirstlane(__float_as_int(mdB_n.w));
        uint2 rA_n = ldxl(sAn), rB_n = ldxl(sBn);

        float xl0[CPL], xl1[CPL];
        if constexpr (CPL == 4) {
            unpack2(rA.x, xl0[0], xl0[1]); unpack2(rA.y, xl0[2], xl0[3]);
            unpack2(rB.x, xl1[0], xl1[1]); unpack2(rB.y, xl1[2], xl1[3]);
        } else {
            unpack2(rA.x, xl0[0], xl0[1]);
            unpack2(rB.x, xl1[0], xl1[1]);
        }
        float p0 = 0.f, p1 = 0.f;
        #pragma unroll
        for (int i = 0; i < CPL; i++) {
            float u0 = fmaf(mdA.x, we0[i],
                       fmaf(mdA.y, we1[i],
                       fmaf(mdA.z, we2[i], xl0[i] + xr[i])));
            float u1 = fmaf(mdB.x, we0[i],
                       fmaf(mdB.y, we1[i],
                       fmaf(mdB.z, we2[i], xl1[i] + xr[i])));
            p0 = fmaf(fmaxf(u0, 0.2f * u0), sa[i], p0);
            p1 = fmaf(fmaxf(u1, 0.2f * u1), sa[i], p1);
        }
        #pragma unroll
        for (int off = GS / 2; off >= 1; off >>= 1) {
            p0 += __shfl_xor(p0, off);
            p1 += __shfl_xor(p1, off);
        }
        if (j + 1 > e1) p1 = -INFINITY;   // odd tail: w1 = 0
        float hi = fmaxf(p0, p1);
        if (__all(hi <= m + 8.f)) {        // defer-max common path
            float w0 = __expf(p0 - m), w1 = __expf(p1 - m);
            l += w0 + w1;
            #pragma unroll
            for (int i = 0; i < CPL; i++)
                acc[i] = fmaf(w0, xl0[i], fmaf(w1, xl1[i], acc[i]));
        } else {                           // rescale path (first iter + rare)
            float mn = fmaxf(m, hi);
            float sc = __expf(m - mn);
            float w0 = __expf(p0 - mn), w1 = __expf(p1 - mn);
            l = fmaf(l, sc, w0 + w1);
            #pragma unroll
            for (int i = 0; i < CPL; i++)
                acc[i] = fmaf(acc[i], sc, fmaf(w0, xl0[i], w1 * xl1[i]));
            m = mn;
        }
        mdA = mdA_n; mdB = mdB_n; rA = rA_n; rB = rB_n;
    }

    float inv = 1.f / (l + 1e-16f);
    float o[CPL];
    float s = 0.f, s2 = 0.f;
    #pragma unroll
    for (int i = 0; i < CPL; i++) {
        o[i] = acc[i] * inv + bo[cb + i];
        s += o[i]; s2 += o[i] * o[i];
    }
    if constexpr (F32OUT) {
        float* q = outf + (size_t)n * HC + cb;
        if constexpr (CPL == 4) {
            *reinterpret_cast<float4*>(q) = make_float4(o[0], o[1], o[2], o[3]);
        } else {
            *reinterpret_cast<float2*>(q) = make_float2(o[0], o[1]);
        }
    } else {
        u16* q = outb + (size_t)n * HC + cb;
        if constexpr (CPL == 4) {
            *reinterpret_cast<uint2*>(q) =
                make_uint2(pack2(o[0], o[1]), pack2(o[2], o[3]));
        } else {
            *reinterpret_cast<unsigned*>(q) = pack2(o[0], o[1]);
        }
    }
    #pragma unroll
    for (int off = 32; off; off >>= 1) {
        s += __shfl_xor(s, off);
        s2 += __shfl_xor(s2, off);
    }
    if (lane == 0) {
        double* bk = sbuck + (size_t)(blockIdx.x & 511) * 2;
        atomicAdd(bk, (double)s);
        atomicAdd(bk + 1, (double)s2);
    }
}

// ---------------------------------------------------------------- pooling: fused LN finalize + LN+ELU + goff search

__global__ __launch_bounds__(256) void pool_ln(const float* __restrict__ h,
                                               const int* __restrict__ batch,
                                               const double* __restrict__ buck,
                                               double count,
                                               const float* __restrict__ lw,
                                               const float* __restrict__ lb,
                                               float* __restrict__ out, int N) {
    float2 lp = reduce_buckets(buck, count);
    __shared__ float sh[128], mh[128];
    int g = blockIdx.x;
    int s_ = 0, hi_ = N;
    while (s_ < hi_) { int mid = (s_ + hi_) >> 1; if (batch[mid] < g) s_ = mid + 1; else hi_ = mid; }
    int e_ = s_, hi2 = N;
    while (e_ < hi2) { int mid = (e_ + hi2) >> 1; if (batch[mid] < g + 1) e_ = mid + 1; else hi2 = mid; }
    int tid = threadIdx.x;
    int c = tid & 127, part = tid >> 7;
    float wc = lw[c] * lp.y, bc = lb[c];
    float sum = 0.f, mx = -INFINITY;
    for (int n = s_ + part; n < e_; n += 2) {
        float v = (h[(size_t)n * 128 + c] - lp.x) * wc + bc;
        v = v > 0.f ? v : expm1f(v);
        sum += v;
        mx = fmaxf(mx, v);
    }
    if (part == 1) { sh[c] = sum; mh[c] = mx; }
    __syncthreads();
    if (part == 0) {
        if (e_ - s_ > 1) { sum += sh[c]; mx = fmaxf(mx, mh[c]); }
        int cnt = e_ - s_;
        out[g * 256 + c] = cnt > 0 ? sum / (float)cnt : 0.f;
        out[g * 256 + 128 + c] = cnt > 0 ? mx : 0.f;
    }
}

// ---------------------------------------------------------------- launch

extern "C" void kernel_launch(void* const* d_in, const int* in_sizes, int n_in,
                              void* d_out, int out_size, void* d_ws, size_t ws_size,
                              hipStream_t stream) {
    const int N = N_NODES, E = N_EDGES, G = N_GRAPHS, E2 = E2_TOTAL;
    const float* x = (const float*)d_in[0];
    const int* ei = (const int*)d_in[1];
    const float* eattr = (const float*)d_in[2];
    const int* batch = (const int*)d_in[3];
    auto P = [&](int l, int k) { return (const float*)d_in[4 + l * 9 + k]; };
    // k: 0=Wl 1=bl 2=Wr 3=br 4=We 5=att 6=bo 7=lnw 8=lnb

    char* w = (char*)d_ws;
    size_t off = 0;
    auto alloc = [&](size_t bytes) -> void* {
        void* p = w + off;
        off += (bytes + 255) & ~(size_t)255;
        return p;
    };
    u16* Xa = (u16*)alloc((size_t)N * 512 * 2);      // XL per layer
    u16* Xb = (u16*)alloc((size_t)N * 512 * 2);      // XR per layer
    u16* Xc = (u16*)alloc((size_t)N * 512 * 2);      // raw attn out per layer
    float* H3f = (float*)alloc((size_t)N * 128 * 4); // layer-3 attn out fp32
    float4* meta = (float4*)alloc((size_t)E2 * 16);  // CSR-ordered {ea, src}
    u16* WtL = (u16*)alloc((size_t)512 * 256 * 2);
    u16* WtR = (u16*)alloc((size_t)512 * 256 * 2);
    int* rowptr = (int*)alloc((size_t)(N + 1) * 4);
    int* cursor = (int*)alloc((size_t)N * 4);
    // zero-initialized region: [zs, ze)
    size_t zs = off;
    int* deg = (int*)alloc((size_t)N * 4);
    float* asum = (float*)alloc((size_t)N * 3 * 4);
    double* b1 = (double*)alloc(512 * 2 * 8);
    double* b2 = (double*)alloc(512 * 2 * 8);
    double* b3 = (double*)alloc(512 * 2 * 8);
    size_t ze = off;
    (void)ws_size; (void)n_in; (void)in_sizes; (void)out_size;

    hipMemsetAsync(w + zs, 0, ze - zs, stream);

    deg_kernel<<<(E + 255) / 256, 256, 0, stream>>>(ei, eattr, deg, asum, E);
    scan_kernel<<<1, 1024, 0, stream>>>(deg, rowptr, cursor, N);
    fill_kernel<<<(E2 + 255) / 256, 256, 0, stream>>>(ei, eattr, asum, deg, cursor,
                                                      meta, E, E2);

    // -------- layer 1 (din=8, H=4, HC=512): 2 waves/node, gather path
    xw8_dual<<<(N + 63) / 64, 256, 0, stream>>>(x, P(0, 0), P(0, 1), P(0, 2), P(0, 3),
                                                Xa, Xb, N);
    attn_wave<512, 2, false><<<(N * 2 + 3) / 4, 256, 0, stream>>>(
        rowptr, meta, Xa, Xb, P(0, 4), P(0, 5), P(0, 6), nullptr, Xc, b1, N);

    // -------- layer 2 (din=512, H=2, HC=256); LN+ELU fused into gemm A-path
    {
        dim3 tg(512 / 64, 256 / 64, 2);
        wt_dual<<<tg, 256, 0, stream>>>(P(1, 0), P(1, 2), WtL, WtR, 512, 256);
        dim3 gg((N + 127) / 128, 2, 2);
        gemm_dual<<<gg, 256, 0, stream>>>(Xc, WtL, WtR, P(1, 1), P(1, 3),
                                          Xa, Xb, b1, (double)N * 512.0,
                                          P(0, 7), P(0, 8), N, 512, 256);
    }
    attn_wave<256, 1, false><<<(N + 3) / 4, 256, 0, stream>>>(
        rowptr, meta, Xa, Xb, P(1, 4), P(1, 5), P(1, 6), nullptr, Xc, b2, N);

    // -------- layer 3 (din=256, H=1, HC=128); LN+ELU fused into gemm A-path
    {
        dim3 tg(256 / 64, 128 / 64, 2);
        wt_dual<<<tg, 256, 0, stream>>>(P(2, 0), P(2, 2), WtL, WtR, 256, 128);
        dim3 gg((N + 127) / 128, 1, 2);
        gemm_dual<<<gg, 256, 0, stream>>>(Xc, WtL, WtR, P(2, 1), P(2, 3),
                                          Xa, Xb, b2, (double)N * 256.0,
                                          P(1, 7), P(1, 8), N, 256, 128);
    }
    attn_wave<128, 1, true><<<(N + 3) / 4, 256, 0, stream>>>(
        rowptr, meta, Xa, Xb, P(2, 4), P(2, 5), P(2, 6), H3f, nullptr, b3, N);

    // -------- pooling (fused LN finalize + apply + goff search)
    pool_ln<<<G, 256, 0, stream>>>(H3f, batch, b3, (double)N * 128.0,
                                   P(2, 7), P(2, 8), (float*)d_out, N);
}

// Round 10
// 873.196 us; speedup vs baseline: 1.3004x; 1.1309x over previous
//
#include <hip/hip_runtime.h>
#include <hip/hip_bf16.h>
#include <math.h>

#define N_NODES 50000
#define N_EDGES 800000
#define N_GRAPHS 64
#define E2_TOTAL (N_EDGES + N_NODES)

typedef unsigned short u16;
typedef __attribute__((ext_vector_type(8))) short s16x8;
typedef __attribute__((ext_vector_type(4))) float f32x4;

__device__ __forceinline__ u16 f2bf(float f) {
    unsigned u = __float_as_uint(f);
    u += 0x7fffu + ((u >> 16) & 1u);   // round-to-nearest-even
    return (u16)(u >> 16);
}
__device__ __forceinline__ void unpack2(unsigned v, float& a, float& b) {
    a = __uint_as_float(v << 16);
    b = __uint_as_float(v & 0xffff0000u);
}
__device__ __forceinline__ unsigned pack2(float a, float b) {
    return (unsigned)f2bf(a) | ((unsigned)f2bf(b) << 16);
}
__device__ __forceinline__ float elu_fast(float u) {
    return u > 0.f ? u : __expf(u) - 1.f;
}

// ---------------------------------------------------------------- CSR build

__global__ __launch_bounds__(256) void deg_kernel(const int* __restrict__ ei,
                                                  const float* __restrict__ eattr,
                                                  int* __restrict__ deg,
                                                  float* __restrict__ asum, int E) {
    int e = blockIdx.x * 256 + threadIdx.x;
    if (e >= E) return;
    int dst = ei[E + e];
    atomicAdd(&deg[dst], 1);
    atomicAdd(&asum[dst * 3 + 0], eattr[e * 3 + 0]);
    atomicAdd(&asum[dst * 3 + 1], eattr[e * 3 + 1]);
    atomicAdd(&asum[dst * 3 + 2], eattr[e * 3 + 2]);
}

// exclusive scan of (deg+1); writes rowptr AND cursor
__global__ __launch_bounds__(1024) void scan_kernel(const int* __restrict__ deg,
                                                    int* __restrict__ rowptr,
                                                    int* __restrict__ cursor, int N) {
    __shared__ int wsum[16];
    __shared__ int carry_s;
    int tid = threadIdx.x, lane = tid & 63, wid = tid >> 6;
    if (tid == 0) carry_s = 0;
    __syncthreads();
    for (int base = 0; base < N; base += 4096) {
        int i0 = base + tid * 4;
        int d0 = (i0 + 0 < N) ? deg[i0 + 0] + 1 : 0;
        int d1 = (i0 + 1 < N) ? deg[i0 + 1] + 1 : 0;
        int d2 = (i0 + 2 < N) ? deg[i0 + 2] + 1 : 0;
        int d3 = (i0 + 3 < N) ? deg[i0 + 3] + 1 : 0;
        int v = d0 + d1 + d2 + d3;
        int x = v;
        #pragma unroll
        for (int off = 1; off < 64; off <<= 1) {
            int t = __shfl_up(x, off);
            if (lane >= off) x += t;
        }
        if (lane == 63) wsum[wid] = x;
        __syncthreads();
        if (wid == 0) {
            int y = (lane < 16) ? wsum[lane] : 0;
            #pragma unroll
            for (int off = 1; off < 16; off <<= 1) {
                int t = __shfl_up(y, off);
                if (lane >= off) y += t;
            }
            if (lane < 16) wsum[lane] = y;
        }
        __syncthreads();
        int woff = (wid > 0) ? wsum[wid - 1] : 0;
        int excl = carry_s + woff + x - v;
        if (i0 + 0 < N) { rowptr[i0 + 0] = excl;                cursor[i0 + 0] = excl; }
        if (i0 + 1 < N) { rowptr[i0 + 1] = excl + d0;           cursor[i0 + 1] = excl + d0; }
        if (i0 + 2 < N) { rowptr[i0 + 2] = excl + d0 + d1;      cursor[i0 + 2] = excl + d0 + d1; }
        if (i0 + 3 < N) { rowptr[i0 + 3] = excl + d0 + d1 + d2; cursor[i0 + 3] = excl + d0 + d1 + d2; }
        __syncthreads();
        if (tid == 1023) carry_s += wsum[15];
        __syncthreads();
    }
    if (threadIdx.x == 0) rowptr[N] = carry_s;
}

// CSR fill: meta[pos] = {ea0, ea1, ea2, src}; self-loop attr = asum/deg inline
__global__ __launch_bounds__(256) void fill_kernel(const int* __restrict__ ei,
                                                   const float* __restrict__ eattr,
                                                   const float* __restrict__ asum,
                                                   const int* __restrict__ deg,
                                                   int* __restrict__ cursor,
                                                   float4* __restrict__ meta,
                                                   int E, int E2) {
    int e = blockIdx.x * 256 + threadIdx.x;
    if (e >= E2) return;
    int src, dst;
    float a0, a1, a2;
    if (e < E) {
        src = ei[e]; dst = ei[E + e];
        a0 = eattr[(size_t)e * 3 + 0];
        a1 = eattr[(size_t)e * 3 + 1];
        a2 = eattr[(size_t)e * 3 + 2];
    } else {
        src = e - E; dst = src;
        float inv = 1.0f / (float)max(deg[dst], 1);
        a0 = asum[(size_t)dst * 3 + 0] * inv;
        a1 = asum[(size_t)dst * 3 + 1] * inv;
        a2 = asum[(size_t)dst * 3 + 2] * inv;
    }
    int pos = atomicAdd(&cursor[dst], 1);
    meta[pos] = make_float4(a0, a1, a2, __int_as_float(src));
}

// ---------------------------------------------------------------- X1 = x@W+b (din=8), both L and R -> bf16

__global__ __launch_bounds__(256) void xw8_dual(const float* __restrict__ x,
                                                const float* __restrict__ Wl,
                                                const float* __restrict__ bl,
                                                const float* __restrict__ Wr,
                                                const float* __restrict__ br,
                                                u16* __restrict__ Xa,
                                                u16* __restrict__ Xb, int N) {
    __shared__ float sWl[8 * 512], sWr[8 * 512];
    __shared__ float sbl[512], sbr[512];
    __shared__ float sx[64][8];
    int tid = threadIdx.x;
    int nb = blockIdx.x * 64;
    for (int i = tid; i < 8 * 512; i += 256) { sWl[i] = Wl[i]; sWr[i] = Wr[i]; }
    for (int i = tid; i < 512; i += 256) { sbl[i] = bl[i]; sbr[i] = br[i]; }
    for (int i = tid; i < 64 * 8; i += 256) {
        int j = i >> 3, k = i & 7;
        int n = nb + j;
        sx[j][k] = (n < N) ? x[(size_t)n * 8 + k] : 0.f;
    }
    __syncthreads();
    for (int it = 0; it < 64; it++) {
        int i = tid + it * 256;
        int j = i >> 8, c2 = (i & 255) * 2;
        int n = nb + j;
        if (n < N) {
            float l0 = sbl[c2], l1 = sbl[c2 + 1];
            float r0 = sbr[c2], r1 = sbr[c2 + 1];
            #pragma unroll
            for (int k = 0; k < 8; k++) {
                float xv = sx[j][k];
                l0 += xv * sWl[k * 512 + c2];
                l1 += xv * sWl[k * 512 + c2 + 1];
                r0 += xv * sWr[k * 512 + c2];
                r1 += xv * sWr[k * 512 + c2 + 1];
            }
            *reinterpret_cast<unsigned*>(Xa + (size_t)n * 512 + c2) = pack2(l0, l1);
            *reinterpret_cast<unsigned*>(Xb + (size_t)n * 512 + c2) = pack2(r0, r1);
        }
    }
}

// ---------------------------------------------------------------- bucket reduce helper (in-block, 256 thr)

__device__ __forceinline__ float2 reduce_buckets(const double* __restrict__ buck,
                                                 double count) {
    __shared__ float2 res;
    int t = threadIdx.x;
    double s  = buck[t * 2]     + buck[(t + 256) * 2];
    double s2 = buck[t * 2 + 1] + buck[(t + 256) * 2 + 1];
    #pragma unroll
    for (int off = 32; off; off >>= 1) {
        s += __shfl_xor(s, off);
        s2 += __shfl_xor(s2, off);
    }
    __shared__ double a[4], b[4];
    int wid = t >> 6, lane = t & 63;
    if (lane == 0) { a[wid] = s; b[wid] = s2; }
    __syncthreads();
    if (t == 0) {
        double S = a[0] + a[1] + a[2] + a[3];
        double S2 = b[0] + b[1] + b[2] + b[3];
        double mu = S / count;
        double var = S2 / count - mu * mu;
        float sd = (float)sqrt(var > 0.0 ? var : 0.0);
        res.x = (float)mu;
        res.y = 1.f / (sd + 1e-5f);
    }
    __syncthreads();
    return res;
}

// ---------------------------------------------------------------- W -> Wt bf16 transpose (dual via blockIdx.z)

__global__ __launch_bounds__(256) void wt_dual(const float* __restrict__ WL,
                                               const float* __restrict__ WR,
                                               u16* __restrict__ WtL,
                                               u16* __restrict__ WtR, int K, int M) {
    const float* W = blockIdx.z ? WR : WL;
    u16* Wt = blockIdx.z ? WtR : WtL;
    __shared__ u16 t[64][65];
    int kb = blockIdx.x * 64, mb = blockIdx.y * 64;
    int tid = threadIdx.x;
    for (int i = tid; i < 64 * 64; i += 256) {
        int k = i >> 6, m = i & 63;
        t[m][k] = f2bf(W[(size_t)(kb + k) * M + mb + m]);
    }
    __syncthreads();
    for (int i = tid; i < 64 * 64; i += 256) {
        int m = i >> 6, k = i & 63;
        Wt[(size_t)(mb + m) * K + kb + k] = t[m][k];
    }
}

// ---------------------------------------------------------------- MFMA GEMM (bf16), dual via blockIdx.z
// A-staging applies fused LayerNorm + fast-ELU. LDS: stride=BK (bank-period),
// XOR swizzle of 8-elem col-blocks (cb ^ (row&7)) on write AND read ->
// conflict-free ds_read_b128 across the 16-row fragment stripe.

__global__ __launch_bounds__(256) void gemm_dual(const u16* __restrict__ A,
                                                 const u16* __restrict__ BtL,
                                                 const u16* __restrict__ BtR,
                                                 const float* __restrict__ biasL,
                                                 const float* __restrict__ biasR,
                                                 u16* __restrict__ YL,
                                                 u16* __restrict__ YR,
                                                 const double* __restrict__ buck,
                                                 double count,
                                                 const float* __restrict__ lnw,
                                                 const float* __restrict__ lnb,
                                                 int N, int K, int M) {
    const u16* Bt = blockIdx.z ? BtR : BtL;
    const float* bias = blockIdx.z ? biasR : biasL;
    u16* Y = blockIdx.z ? YR : YL;
    constexpr int BM = 128, BK = 64;
    __shared__ u16 As[BM][BK];
    __shared__ u16 Bs[BM][BK];
    __shared__ float sLw[512], sLb[512];
    float2 lp = reduce_buckets(buck, count);
    float muf = lp.x, rs = lp.y;
    int tid = threadIdx.x;
    for (int i = tid; i < K; i += 256) { sLw[i] = lnw[i] * rs; sLb[i] = lnb[i]; }
    int wid = tid >> 6, lane = tid & 63;
    int wm = (wid >> 1) * 64, wn = (wid & 1) * 64;
    int bm = blockIdx.x * BM, bn = blockIdx.y * BM;
    int l15 = lane & 15, l4 = lane >> 4;
    f32x4 acc[4][4] = {};
    int sr = tid >> 3;            // 0..31
    int cbw = tid & 7;            // col-block 0..7
    int sc = cbw * 8;
    __syncthreads();

    for (int k0 = 0; k0 < K; k0 += BK) {
        #pragma unroll
        for (int p = 0; p < 4; p++) {
            int r = p * 32 + sr;
            int swc = ((cbw ^ (r & 7)) * 8);
            int grow = bm + r;
            uint4 av = make_uint4(0, 0, 0, 0);
            if (grow < N) {
                av = *reinterpret_cast<const uint4*>(A + (size_t)grow * K + k0 + sc);
                float f[8];
                unpack2(av.x, f[0], f[1]); unpack2(av.y, f[2], f[3]);
                unpack2(av.z, f[4], f[5]); unpack2(av.w, f[6], f[7]);
                #pragma unroll
                for (int q = 0; q < 8; q++) {
                    int c = k0 + sc + q;
                    f[q] = elu_fast((f[q] - muf) * sLw[c] + sLb[c]);
                }
                av = make_uint4(pack2(f[0], f[1]), pack2(f[2], f[3]),
                                pack2(f[4], f[5]), pack2(f[6], f[7]));
            }
            *reinterpret_cast<uint4*>(&As[r][swc]) = av;
            uint4 bv = *reinterpret_cast<const uint4*>(Bt + (size_t)(bn + r) * K + k0 + sc);
            *reinterpret_cast<uint4*>(&Bs[r][swc]) = bv;
        }
        __syncthreads();
        #pragma unroll
        for (int kk = 0; kk < 2; kk++) {
            int CB = kk * 4 + l4;     // col-block 0..7
            s16x8 af[4], bfr[4];
            #pragma unroll
            for (int i = 0; i < 4; i++) {
                int Ra = wm + i * 16 + l15;
                int Rb = wn + i * 16 + l15;
                af[i]  = *reinterpret_cast<const s16x8*>(&As[Ra][(CB ^ (Ra & 7)) * 8]);
                bfr[i] = *reinterpret_cast<const s16x8*>(&Bs[Rb][(CB ^ (Rb & 7)) * 8]);
            }
            #pragma unroll
            for (int i = 0; i < 4; i++)
                #pragma unroll
                for (int j = 0; j < 4; j++)
                    acc[i][j] = __builtin_amdgcn_mfma_f32_16x16x32_bf16(
                        af[i], bfr[j], acc[i][j], 0, 0, 0);
        }
        __syncthreads();
    }
    #pragma unroll
    for (int i = 0; i < 4; i++) {
        #pragma unroll
        for (int j = 0; j < 4; j++) {
            int col = bn + wn + j * 16 + l15;
            float bv = bias[col];
            #pragma unroll
            for (int r = 0; r < 4; r++) {
                int row = bm + wm + i * 16 + l4 * 4 + r;
                if (row < N)
                    Y[(size_t)row * M + col] = f2bf(acc[i][j][r] + bv);
            }
        }
    }
}

// ---------------------------------------------------------------- wave-per-node GATv2
// SPLIT waves per node; scalar meta loads; bf16 XL gather; 2 edges/iter with
// 2-ahead prefetch; defer-max online softmax; fused LN-stat bucket atomics.

template <int HC, int SPLIT, bool F32OUT>
__global__ __launch_bounds__(256) void attn_wave(
    const int* __restrict__ rowptr, const float4* __restrict__ meta,
    const u16* __restrict__ XLbf, const u16* __restrict__ XRbf,
    const float* __restrict__ We, const float* __restrict__ att,
    const float* __restrict__ bo, float* __restrict__ outf,
    u16* __restrict__ outb, double* __restrict__ sbuck, int N) {
    constexpr int CW  = HC / SPLIT;   // channels per wave
    constexpr int CPL = CW / 64;      // 4 or 2
    constexpr int GS  = 128 / CPL;    // lanes per head group (32 or 64)
    int gw = blockIdx.x * 4 + (threadIdx.x >> 6);
    int lane = threadIdx.x & 63;
    int n = gw / SPLIT;
    int sub = gw - n * SPLIT;
    if (n >= N) return;
    int cb = sub * CW + lane * CPL;

    float xr[CPL], we0[CPL], we1[CPL], we2[CPL], sa[CPL], acc[CPL];
    #pragma unroll
    for (int i = 0; i < CPL; i++) {
        we0[i] = We[cb + i];
        we1[i] = We[HC + cb + i];
        we2[i] = We[2 * HC + cb + i];
        sa[i]  = att[cb + i];
        acc[i] = 0.f;
    }
    {
        const u16* p = XRbf + (size_t)n * HC + cb;
        if constexpr (CPL == 4) {
            uint2 r = *reinterpret_cast<const uint2*>(p);
            unpack2(r.x, xr[0], xr[1]); unpack2(r.y, xr[2], xr[3]);
        } else {
            unsigned r = *reinterpret_cast<const unsigned*>(p);
            unpack2(r, xr[0], xr[1]);
        }
    }

    auto ldxl = [&](int src) -> uint2 {
        const u16* p = XLbf + (size_t)src * HC + cb;
        if constexpr (CPL == 4) {
            return *reinterpret_cast<const uint2*>(p);
        } else {
            uint2 r; r.x = *reinterpret_cast<const unsigned*>(p); r.y = 0;
            return r;
        }
    };

    int beg = __builtin_amdgcn_readfirstlane(rowptr[n]);
    int end = __builtin_amdgcn_readfirstlane(rowptr[n + 1]);
    int e1 = end - 1;
    float m = -INFINITY, l = 0.f;

    float4 mdA = meta[beg];
    float4 mdB = meta[min(beg + 1, e1)];
    int sA = __builtin_amdgcn_readfirstlane(__float_as_int(mdA.w));
    int sB = __builtin_amdgcn_readfirstlane(__float_as_int(mdB.w));
    uint2 rA = ldxl(sA), rB = ldxl(sB);

    for (int j = beg; j < end; j += 2) {
        float4 mdA_n = meta[min(j + 2, e1)];
        float4 mdB_n = meta[min(j + 3, e1)];
        int sAn = __builtin_amdgcn_readfirstlane(__float_as_int(mdA_n.w));
        int sBn = __builtin_amdgcn_readfirstlane(__float_as_int(mdB_n.w));
        uint2 rA_n = ldxl(sAn), rB_n = ldxl(sBn);

        float xl0[CPL], xl1[CPL];
        if constexpr (CPL == 4) {
            unpack2(rA.x, xl0[0], xl0[1]); unpack2(rA.y, xl0[2], xl0[3]);
            unpack2(rB.x, xl1[0], xl1[1]); unpack2(rB.y, xl1[2], xl1[3]);
        } else {
            unpack2(rA.x, xl0[0], xl0[1]);
            unpack2(rB.x, xl1[0], xl1[1]);
        }
        float p0 = 0.f, p1 = 0.f;
        #pragma unroll
        for (int i = 0; i < CPL; i++) {
            float u0 = fmaf(mdA.x, we0[i],
                       fmaf(mdA.y, we1[i],
                       fmaf(mdA.z, we2[i], xl0[i] + xr[i])));
            float u1 = fmaf(mdB.x, we0[i],
                       fmaf(mdB.y, we1[i],
                       fmaf(mdB.z, we2[i], xl1[i] + xr[i])));
            p0 = fmaf(fmaxf(u0, 0.2f * u0), sa[i], p0);
            p1 = fmaf(fmaxf(u1, 0.2f * u1), sa[i], p1);
        }
        #pragma unroll
        for (int off = GS / 2; off >= 1; off >>= 1) {
            p0 += __shfl_xor(p0, off);
            p1 += __shfl_xor(p1, off);
        }
        if (j + 1 > e1) p1 = -INFINITY;   // odd tail: w1 = 0
        float hi = fmaxf(p0, p1);
        if (__all(hi <= m + 8.f)) {        // defer-max common path
            float w0 = __expf(p0 - m), w1 = __expf(p1 - m);
            l += w0 + w1;
            #pragma unroll
            for (int i = 0; i < CPL; i++)
                acc[i] = fmaf(w0, xl0[i], fmaf(w1, xl1[i], acc[i]));
        } else {                           // rescale path (first iter + rare)
            float mn = fmaxf(m, hi);
            float sc = __expf(m - mn);
            float w0 = __expf(p0 - mn), w1 = __expf(p1 - mn);
            l = fmaf(l, sc, w0 + w1);
            #pragma unroll
            for (int i = 0; i < CPL; i++)
                acc[i] = fmaf(acc[i], sc, fmaf(w0, xl0[i], w1 * xl1[i]));
            m = mn;
        }
        mdA = mdA_n; mdB = mdB_n; rA = rA_n; rB = rB_n;
    }

    float inv = 1.f / (l + 1e-16f);
    float o[CPL];
    float s = 0.f, s2 = 0.f;
    #pragma unroll
    for (int i = 0; i < CPL; i++) {
        o[i] = acc[i] * inv + bo[cb + i];
        s += o[i]; s2 += o[i] * o[i];
    }
    if constexpr (F32OUT) {
        float* q = outf + (size_t)n * HC + cb;
        if constexpr (CPL == 4) {
            *reinterpret_cast<float4*>(q) = make_float4(o[0], o[1], o[2], o[3]);
        } else {
            *reinterpret_cast<float2*>(q) = make_float2(o[0], o[1]);
        }
    } else {
        u16* q = outb + (size_t)n * HC + cb;
        if constexpr (CPL == 4) {
            *reinterpret_cast<uint2*>(q) =
                make_uint2(pack2(o[0], o[1]), pack2(o[2], o[3]));
        } else {
            *reinterpret_cast<unsigned*>(q) = pack2(o[0], o[1]);
        }
    }
    #pragma unroll
    for (int off = 32; off; off >>= 1) {
        s += __shfl_xor(s, off);
        s2 += __shfl_xor(s2, off);
    }
    if (lane == 0) {
        double* bk = sbuck + (size_t)(blockIdx.x & 511) * 2;
        atomicAdd(bk, (double)s);
        atomicAdd(bk + 1, (double)s2);
    }
}

// ---------------------------------------------------------------- pooling: fused LN finalize + LN+ELU + goff search

__global__ __launch_bounds__(256) void pool_ln(const float* __restrict__ h,
                                               const int* __restrict__ batch,
                                               const double* __restrict__ buck,
                                               double count,
                                               const float* __restrict__ lw,
                                               const float* __restrict__ lb,
                                               float* __restrict__ out, int N) {
    float2 lp = reduce_buckets(buck, count);
    __shared__ float sh[128], mh[128];
    int g = blockIdx.x;
    int s_ = 0, hi_ = N;
    while (s_ < hi_) { int mid = (s_ + hi_) >> 1; if (batch[mid] < g) s_ = mid + 1; else hi_ = mid; }
    int e_ = s_, hi2 = N;
    while (e_ < hi2) { int mid = (e_ + hi2) >> 1; if (batch[mid] < g + 1) e_ = mid + 1; else hi2 = mid; }
    int tid = threadIdx.x;
    int c = tid & 127, part = tid >> 7;
    float wc = lw[c] * lp.y, bc = lb[c];
    float sum = 0.f, mx = -INFINITY;
    for (int n = s_ + part; n < e_; n += 2) {
        float v = elu_fast((h[(size_t)n * 128 + c] - lp.x) * wc + bc);
        sum += v;
        mx = fmaxf(mx, v);
    }
    if (part == 1) { sh[c] = sum; mh[c] = mx; }
    __syncthreads();
    if (part == 0) {
        if (e_ - s_ > 1) { sum += sh[c]; mx = fmaxf(mx, mh[c]); }
        int cnt = e_ - s_;
        out[g * 256 + c] = cnt > 0 ? sum / (float)cnt : 0.f;
        out[g * 256 + 128 + c] = cnt > 0 ? mx : 0.f;
    }
}

// ---------------------------------------------------------------- launch

extern "C" void kernel_launch(void* const* d_in, const int* in_sizes, int n_in,
                              void* d_out, int out_size, void* d_ws, size_t ws_size,
                              hipStream_t stream) {
    const int N = N_NODES, E = N_EDGES, G = N_GRAPHS, E2 = E2_TOTAL;
    const float* x = (const float*)d_in[0];
    const int* ei = (const int*)d_in[1];
    const float* eattr = (const float*)d_in[2];
    const int* batch = (const int*)d_in[3];
    auto P = [&](int l, int k) { return (const float*)d_in[4 + l * 9 + k]; };
    // k: 0=Wl 1=bl 2=Wr 3=br 4=We 5=att 6=bo 7=lnw 8=lnb

    char* w = (char*)d_ws;
    size_t off = 0;
    auto alloc = [&](size_t bytes) -> void* {
        void* p = w + off;
        off += (bytes + 255) & ~(size_t)255;
        return p;
    };
    u16* Xa = (u16*)alloc((size_t)N * 512 * 2);      // XL per layer
    u16* Xb = (u16*)alloc((size_t)N * 512 * 2);      // XR per layer
    u16* Xc = (u16*)alloc((size_t)N * 512 * 2);      // raw attn out per layer
    float* H3f = (float*)alloc((size_t)N * 128 * 4); // layer-3 attn out fp32
    float4* meta = (float4*)alloc((size_t)E2 * 16);  // CSR-ordered {ea, src}
    u16* WtL = (u16*)alloc((size_t)512 * 256 * 2);
    u16* WtR = (u16*)alloc((size_t)512 * 256 * 2);
    int* rowptr = (int*)alloc((size_t)(N + 1) * 4);
    int* cursor = (int*)alloc((size_t)N * 4);
    // zero-initialized region: [zs, ze)
    size_t zs = off;
    int* deg = (int*)alloc((size_t)N * 4);
    float* asum = (float*)alloc((size_t)N * 3 * 4);
    double* b1 = (double*)alloc(512 * 2 * 8);
    double* b2 = (double*)alloc(512 * 2 * 8);
    double* b3 = (double*)alloc(512 * 2 * 8);
    size_t ze = off;
    (void)ws_size; (void)n_in; (void)in_sizes; (void)out_size;

    hipMemsetAsync(w + zs, 0, ze - zs, stream);

    deg_kernel<<<(E + 255) / 256, 256, 0, stream>>>(ei, eattr, deg, asum, E);
    scan_kernel<<<1, 1024, 0, stream>>>(deg, rowptr, cursor, N);
    fill_kernel<<<(E2 + 255) / 256, 256, 0, stream>>>(ei, eattr, asum, deg, cursor,
                                                      meta, E, E2);

    // -------- layer 1 (din=8, H=4, HC=512): 2 waves/node, gather path
    xw8_dual<<<(N + 63) / 64, 256, 0, stream>>>(x, P(0, 0), P(0, 1), P(0, 2), P(0, 3),
                                                Xa, Xb, N);
    attn_wave<512, 2, false><<<(N * 2 + 3) / 4, 256, 0, stream>>>(
        rowptr, meta, Xa, Xb, P(0, 4), P(0, 5), P(0, 6), nullptr, Xc, b1, N);

    // -------- layer 2 (din=512, H=2, HC=256); LN+ELU fused into gemm A-path
    {
        dim3 tg(512 / 64, 256 / 64, 2);
        wt_dual<<<tg, 256, 0, stream>>>(P(1, 0), P(1, 2), WtL, WtR, 512, 256);
        dim3 gg((N + 127) / 128, 2, 2);
        gemm_dual<<<gg, 256, 0, stream>>>(Xc, WtL, WtR, P(1, 1), P(1, 3),
                                          Xa, Xb, b1, (double)N * 512.0,
                                          P(0, 7), P(0, 8), N, 512, 256);
    }
    attn_wave<256, 1, false><<<(N + 3) / 4, 256, 0, stream>>>(
        rowptr, meta, Xa, Xb, P(1, 4), P(1, 5), P(1, 6), nullptr, Xc, b2, N);

    // -------- layer 3 (din=256, H=1, HC=128); LN+ELU fused into gemm A-path
    {
        dim3 tg(256 / 64, 128 / 64, 2);
        wt_dual<<<tg, 256, 0, stream>>>(P(2, 0), P(2, 2), WtL, WtR, 256, 128);
        dim3 gg((N + 127) / 128, 1, 2);
        gemm_dual<<<gg, 256, 0, stream>>>(Xc, WtL, WtR, P(2, 1), P(2, 3),
                                          Xa, Xb, b2, (double)N * 256.0,
                                          P(1, 7), P(1, 8), N, 256, 128);
    }
    attn_wave<128, 1, true><<<(N + 3) / 4, 256, 0, stream>>>(
        rowptr, meta, Xa, Xb, P(2, 4), P(2, 5), P(2, 6), H3f, nullptr, b3, N);

    // -------- pooling (fused LN finalize + apply + goff search)
    pool_ln<<<G, 256, 0, stream>>>(H3f, batch, b3, (double)N * 128.0,
                                   P(2, 7), P(2, 8), (float*)d_out, N);
}

// Round 11
// 867.082 us; speedup vs baseline: 1.3095x; 1.0071x over previous
//
#include <hip/hip_runtime.h>
#include <hip/hip_bf16.h>
#include <math.h>

#define N_NODES 50000
#define N_EDGES 800000
#define N_GRAPHS 64
#define E2_TOTAL (N_EDGES + N_NODES)

typedef unsigned short u16;
typedef __attribute__((ext_vector_type(8))) short s16x8;
typedef __attribute__((ext_vector_type(4))) float f32x4;

__device__ __forceinline__ u16 f2bf(float f) {
    unsigned u = __float_as_uint(f);
    u += 0x7fffu + ((u >> 16) & 1u);   // round-to-nearest-even
    return (u16)(u >> 16);
}
__device__ __forceinline__ void unpack2(unsigned v, float& a, float& b) {
    a = __uint_as_float(v << 16);
    b = __uint_as_float(v & 0xffff0000u);
}
__device__ __forceinline__ unsigned pack2(float a, float b) {
    return (unsigned)f2bf(a) | ((unsigned)f2bf(b) << 16);
}
__device__ __forceinline__ float elu_fast(float u) {
    return u > 0.f ? u : __expf(u) - 1.f;
}

// ---------------------------------------------------------------- CSR build

__global__ __launch_bounds__(256) void deg_kernel(const int* __restrict__ ei,
                                                  const float* __restrict__ eattr,
                                                  int* __restrict__ deg,
                                                  float* __restrict__ asum, int E) {
    int e = blockIdx.x * 256 + threadIdx.x;
    if (e >= E) return;
    int dst = ei[E + e];
    atomicAdd(&deg[dst], 1);
    atomicAdd(&asum[dst * 3 + 0], eattr[e * 3 + 0]);
    atomicAdd(&asum[dst * 3 + 1], eattr[e * 3 + 1]);
    atomicAdd(&asum[dst * 3 + 2], eattr[e * 3 + 2]);
}

// exclusive scan of (deg+1); writes rowptr AND cursor
__global__ __launch_bounds__(1024) void scan_kernel(const int* __restrict__ deg,
                                                    int* __restrict__ rowptr,
                                                    int* __restrict__ cursor, int N) {
    __shared__ int wsum[16];
    __shared__ int carry_s;
    int tid = threadIdx.x, lane = tid & 63, wid = tid >> 6;
    if (tid == 0) carry_s = 0;
    __syncthreads();
    for (int base = 0; base < N; base += 4096) {
        int i0 = base + tid * 4;
        int d0 = (i0 + 0 < N) ? deg[i0 + 0] + 1 : 0;
        int d1 = (i0 + 1 < N) ? deg[i0 + 1] + 1 : 0;
        int d2 = (i0 + 2 < N) ? deg[i0 + 2] + 1 : 0;
        int d3 = (i0 + 3 < N) ? deg[i0 + 3] + 1 : 0;
        int v = d0 + d1 + d2 + d3;
        int x = v;
        #pragma unroll
        for (int off = 1; off < 64; off <<= 1) {
            int t = __shfl_up(x, off);
            if (lane >= off) x += t;
        }
        if (lane == 63) wsum[wid] = x;
        __syncthreads();
        if (wid == 0) {
            int y = (lane < 16) ? wsum[lane] : 0;
            #pragma unroll
            for (int off = 1; off < 16; off <<= 1) {
                int t = __shfl_up(y, off);
                if (lane >= off) y += t;
            }
            if (lane < 16) wsum[lane] = y;
        }
        __syncthreads();
        int woff = (wid > 0) ? wsum[wid - 1] : 0;
        int excl = carry_s + woff + x - v;
        if (i0 + 0 < N) { rowptr[i0 + 0] = excl;                cursor[i0 + 0] = excl; }
        if (i0 + 1 < N) { rowptr[i0 + 1] = excl + d0;           cursor[i0 + 1] = excl + d0; }
        if (i0 + 2 < N) { rowptr[i0 + 2] = excl + d0 + d1;      cursor[i0 + 2] = excl + d0 + d1; }
        if (i0 + 3 < N) { rowptr[i0 + 3] = excl + d0 + d1 + d2; cursor[i0 + 3] = excl + d0 + d1 + d2; }
        __syncthreads();
        if (tid == 1023) carry_s += wsum[15];
        __syncthreads();
    }
    if (threadIdx.x == 0) rowptr[N] = carry_s;
}

// CSR fill: meta[pos] = {ea0, ea1, ea2, src}; self-loop attr = asum/deg inline
__global__ __launch_bounds__(256) void fill_kernel(const int* __restrict__ ei,
                                                   const float* __restrict__ eattr,
                                                   const float* __restrict__ asum,
                                                   const int* __restrict__ deg,
                                                   int* __restrict__ cursor,
                                                   float4* __restrict__ meta,
                                                   int E, int E2) {
    int e = blockIdx.x * 256 + threadIdx.x;
    if (e >= E2) return;
    int src, dst;
    float a0, a1, a2;
    if (e < E) {
        src = ei[e]; dst = ei[E + e];
        a0 = eattr[(size_t)e * 3 + 0];
        a1 = eattr[(size_t)e * 3 + 1];
        a2 = eattr[(size_t)e * 3 + 2];
    } else {
        src = e - E; dst = src;
        float inv = 1.0f / (float)max(deg[dst], 1);
        a0 = asum[(size_t)dst * 3 + 0] * inv;
        a1 = asum[(size_t)dst * 3 + 1] * inv;
        a2 = asum[(size_t)dst * 3 + 2] * inv;
    }
    int pos = atomicAdd(&cursor[dst], 1);
    meta[pos] = make_float4(a0, a1, a2, __int_as_float(src));
}

// ---------------------------------------------------------------- X1 = x@W+b (din=8), both L and R -> bf16

__global__ __launch_bounds__(256) void xw8_dual(const float* __restrict__ x,
                                                const float* __restrict__ Wl,
                                                const float* __restrict__ bl,
                                                const float* __restrict__ Wr,
                                                const float* __restrict__ br,
                                                u16* __restrict__ Xa,
                                                u16* __restrict__ Xb, int N) {
    __shared__ float sWl[8 * 512], sWr[8 * 512];
    __shared__ float sbl[512], sbr[512];
    __shared__ float sx[64][8];
    int tid = threadIdx.x;
    int nb = blockIdx.x * 64;
    for (int i = tid; i < 8 * 512; i += 256) { sWl[i] = Wl[i]; sWr[i] = Wr[i]; }
    for (int i = tid; i < 512; i += 256) { sbl[i] = bl[i]; sbr[i] = br[i]; }
    for (int i = tid; i < 64 * 8; i += 256) {
        int j = i >> 3, k = i & 7;
        int n = nb + j;
        sx[j][k] = (n < N) ? x[(size_t)n * 8 + k] : 0.f;
    }
    __syncthreads();
    for (int it = 0; it < 64; it++) {
        int i = tid + it * 256;
        int j = i >> 8, c2 = (i & 255) * 2;
        int n = nb + j;
        if (n < N) {
            float l0 = sbl[c2], l1 = sbl[c2 + 1];
            float r0 = sbr[c2], r1 = sbr[c2 + 1];
            #pragma unroll
            for (int k = 0; k < 8; k++) {
                float xv = sx[j][k];
                l0 += xv * sWl[k * 512 + c2];
                l1 += xv * sWl[k * 512 + c2 + 1];
                r0 += xv * sWr[k * 512 + c2];
                r1 += xv * sWr[k * 512 + c2 + 1];
            }
            *reinterpret_cast<unsigned*>(Xa + (size_t)n * 512 + c2) = pack2(l0, l1);
            *reinterpret_cast<unsigned*>(Xb + (size_t)n * 512 + c2) = pack2(r0, r1);
        }
    }
}

// ---------------------------------------------------------------- bucket reduce helper (in-block, 256 thr)

__device__ __forceinline__ float2 reduce_buckets(const double* __restrict__ buck,
                                                 double count) {
    __shared__ float2 res;
    int t = threadIdx.x;
    double s  = buck[t * 2]     + buck[(t + 256) * 2];
    double s2 = buck[t * 2 + 1] + buck[(t + 256) * 2 + 1];
    #pragma unroll
    for (int off = 32; off; off >>= 1) {
        s += __shfl_xor(s, off);
        s2 += __shfl_xor(s2, off);
    }
    __shared__ double a[4], b[4];
    int wid = t >> 6, lane = t & 63;
    if (lane == 0) { a[wid] = s; b[wid] = s2; }
    __syncthreads();
    if (t == 0) {
        double S = a[0] + a[1] + a[2] + a[3];
        double S2 = b[0] + b[1] + b[2] + b[3];
        double mu = S / count;
        double var = S2 / count - mu * mu;
        float sd = (float)sqrt(var > 0.0 ? var : 0.0);
        res.x = (float)mu;
        res.y = 1.f / (sd + 1e-5f);
    }
    __syncthreads();
    return res;
}

// ---------------------------------------------------------------- W -> Wt bf16 transpose (dual via blockIdx.z)

__global__ __launch_bounds__(256) void wt_dual(const float* __restrict__ WL,
                                               const float* __restrict__ WR,
                                               u16* __restrict__ WtL,
                                               u16* __restrict__ WtR, int K, int M) {
    const float* W = blockIdx.z ? WR : WL;
    u16* Wt = blockIdx.z ? WtR : WtL;
    __shared__ u16 t[64][65];
    int kb = blockIdx.x * 64, mb = blockIdx.y * 64;
    int tid = threadIdx.x;
    for (int i = tid; i < 64 * 64; i += 256) {
        int k = i >> 6, m = i & 63;
        t[m][k] = f2bf(W[(size_t)(kb + k) * M + mb + m]);
    }
    __syncthreads();
    for (int i = tid; i < 64 * 64; i += 256) {
        int m = i >> 6, k = i & 63;
        Wt[(size_t)(mb + m) * K + kb + k] = t[m][k];
    }
}

// ---------------------------------------------------------------- MFMA GEMM (bf16), dual via blockIdx.z
// A-staging applies fused LayerNorm + fast-ELU. LDS: stride=BK (bank-period),
// XOR swizzle of 8-elem col-blocks (cb ^ (row&7)) on write AND read.

__global__ __launch_bounds__(256) void gemm_dual(const u16* __restrict__ A,
                                                 const u16* __restrict__ BtL,
                                                 const u16* __restrict__ BtR,
                                                 const float* __restrict__ biasL,
                                                 const float* __restrict__ biasR,
                                                 u16* __restrict__ YL,
                                                 u16* __restrict__ YR,
                                                 const double* __restrict__ buck,
                                                 double count,
                                                 const float* __restrict__ lnw,
                                                 const float* __restrict__ lnb,
                                                 int N, int K, int M) {
    const u16* Bt = blockIdx.z ? BtR : BtL;
    const float* bias = blockIdx.z ? biasR : biasL;
    u16* Y = blockIdx.z ? YR : YL;
    constexpr int BM = 128, BK = 64;
    __shared__ u16 As[BM][BK];
    __shared__ u16 Bs[BM][BK];
    __shared__ float sLw[512], sLb[512];
    float2 lp = reduce_buckets(buck, count);
    float muf = lp.x, rs = lp.y;
    int tid = threadIdx.x;
    for (int i = tid; i < K; i += 256) { sLw[i] = lnw[i] * rs; sLb[i] = lnb[i]; }
    int wid = tid >> 6, lane = tid & 63;
    int wm = (wid >> 1) * 64, wn = (wid & 1) * 64;
    int bm = blockIdx.x * BM, bn = blockIdx.y * BM;
    int l15 = lane & 15, l4 = lane >> 4;
    f32x4 acc[4][4] = {};
    int sr = tid >> 3;            // 0..31
    int cbw = tid & 7;            // col-block 0..7
    int sc = cbw * 8;
    __syncthreads();

    for (int k0 = 0; k0 < K; k0 += BK) {
        #pragma unroll
        for (int p = 0; p < 4; p++) {
            int r = p * 32 + sr;
            int swc = ((cbw ^ (r & 7)) * 8);
            int grow = bm + r;
            uint4 av = make_uint4(0, 0, 0, 0);
            if (grow < N) {
                av = *reinterpret_cast<const uint4*>(A + (size_t)grow * K + k0 + sc);
                float f[8];
                unpack2(av.x, f[0], f[1]); unpack2(av.y, f[2], f[3]);
                unpack2(av.z, f[4], f[5]); unpack2(av.w, f[6], f[7]);
                #pragma unroll
                for (int q = 0; q < 8; q++) {
                    int c = k0 + sc + q;
                    f[q] = elu_fast((f[q] - muf) * sLw[c] + sLb[c]);
                }
                av = make_uint4(pack2(f[0], f[1]), pack2(f[2], f[3]),
                                pack2(f[4], f[5]), pack2(f[6], f[7]));
            }
            *reinterpret_cast<uint4*>(&As[r][swc]) = av;
            uint4 bv = *reinterpret_cast<const uint4*>(Bt + (size_t)(bn + r) * K + k0 + sc);
            *reinterpret_cast<uint4*>(&Bs[r][swc]) = bv;
        }
        __syncthreads();
        #pragma unroll
        for (int kk = 0; kk < 2; kk++) {
            int CB = kk * 4 + l4;     // col-block 0..7
            s16x8 af[4], bfr[4];
            #pragma unroll
            for (int i = 0; i < 4; i++) {
                int Ra = wm + i * 16 + l15;
                int Rb = wn + i * 16 + l15;
                af[i]  = *reinterpret_cast<const s16x8*>(&As[Ra][(CB ^ (Ra & 7)) * 8]);
                bfr[i] = *reinterpret_cast<const s16x8*>(&Bs[Rb][(CB ^ (Rb & 7)) * 8]);
            }
            #pragma unroll
            for (int i = 0; i < 4; i++)
                #pragma unroll
                for (int j = 0; j < 4; j++)
                    acc[i][j] = __builtin_amdgcn_mfma_f32_16x16x32_bf16(
                        af[i], bfr[j], acc[i][j], 0, 0, 0);
        }
        __syncthreads();
    }
    #pragma unroll
    for (int i = 0; i < 4; i++) {
        #pragma unroll
        for (int j = 0; j < 4; j++) {
            int col = bn + wn + j * 16 + l15;
            float bv = bias[col];
            #pragma unroll
            for (int r = 0; r < 4; r++) {
                int row = bm + wm + i * 16 + l4 * 4 + r;
                if (row < N)
                    Y[(size_t)row * M + col] = f2bf(acc[i][j][r] + bv);
            }
        }
    }
}

// ---------------------------------------------------------------- wave-per-node GATv2
// SPLIT waves per node (SPLIT=1 preferred: one wave owns the whole row —
// shuffles/exp/vote/meta amortized over all channels). Scalar meta loads,
// 2 edges/iter with 2-ahead prefetch, defer-max softmax, LN-stat buckets.

template <int HC, int SPLIT, bool F32OUT>
__global__ __launch_bounds__(256) void attn_wave(
    const int* __restrict__ rowptr, const float4* __restrict__ meta,
    const u16* __restrict__ XLbf, const u16* __restrict__ XRbf,
    const float* __restrict__ We, const float* __restrict__ att,
    const float* __restrict__ bo, float* __restrict__ outf,
    u16* __restrict__ outb, double* __restrict__ sbuck, int N) {
    constexpr int CW  = HC / SPLIT;   // channels per wave
    constexpr int CPL = CW / 64;      // 8, 4 or 2
    constexpr int GS  = 128 / CPL;    // lanes per head group (16/32/64)
    int gw = blockIdx.x * 4 + (threadIdx.x >> 6);
    int lane = threadIdx.x & 63;
    int n = gw / SPLIT;
    int sub = gw - n * SPLIT;
    if (n >= N) return;
    int cb = sub * CW + lane * CPL;

    float xr[CPL], we0[CPL], we1[CPL], we2[CPL], sa[CPL], acc[CPL];
    #pragma unroll
    for (int i = 0; i < CPL; i++) {
        we0[i] = We[cb + i];
        we1[i] = We[HC + cb + i];
        we2[i] = We[2 * HC + cb + i];
        sa[i]  = att[cb + i];
        acc[i] = 0.f;
    }
    auto toF = [&](uint4 r, float* v) {
        unpack2(r.x, v[0], v[1]);
        if constexpr (CPL >= 4) unpack2(r.y, v[2], v[3]);
        if constexpr (CPL == 8) { unpack2(r.z, v[4], v[5]); unpack2(r.w, v[6], v[7]); }
    };
    auto ldrow = [&](const u16* base, int idx) -> uint4 {
        const u16* p = base + (size_t)idx * HC + cb;
        if constexpr (CPL == 8) {
            return *reinterpret_cast<const uint4*>(p);
        } else if constexpr (CPL == 4) {
            uint2 r = *reinterpret_cast<const uint2*>(p);
            return make_uint4(r.x, r.y, 0, 0);
        } else {
            return make_uint4(*reinterpret_cast<const unsigned*>(p), 0, 0, 0);
        }
    };
    {
        uint4 r = ldrow(XRbf, n);
        toF(r, xr);
    }

    int beg = __builtin_amdgcn_readfirstlane(rowptr[n]);
    int end = __builtin_amdgcn_readfirstlane(rowptr[n + 1]);
    int e1 = end - 1;
    float m = -INFINITY, l = 0.f;

    float4 mdA = meta[beg];
    float4 mdB = meta[min(beg + 1, e1)];
    int sA = __builtin_amdgcn_readfirstlane(__float_as_int(mdA.w));
    int sB = __builtin_amdgcn_readfirstlane(__float_as_int(mdB.w));
    uint4 rA = ldrow(XLbf, sA), rB = ldrow(XLbf, sB);

    for (int j = beg; j < end; j += 2) {
        float4 mdA_n = meta[min(j + 2, e1)];
        float4 mdB_n = meta[min(j + 3, e1)];
        int sAn = __builtin_amdgcn_readfirstlane(__float_as_int(mdA_n.w));
        int sBn = __builtin_amdgcn_readfirstlane(__float_as_int(mdB_n.w));
        uint4 rA_n = ldrow(XLbf, sAn), rB_n = ldrow(XLbf, sBn);

        float xl0[CPL], xl1[CPL];
        toF(rA, xl0);
        toF(rB, xl1);
        float p0 = 0.f, p1 = 0.f;
        #pragma unroll
        for (int i = 0; i < CPL; i++) {
            float u0 = fmaf(mdA.x, we0[i],
                       fmaf(mdA.y, we1[i],
                       fmaf(mdA.z, we2[i], xl0[i] + xr[i])));
            float u1 = fmaf(mdB.x, we0[i],
                       fmaf(mdB.y, we1[i],
                       fmaf(mdB.z, we2[i], xl1[i] + xr[i])));
            p0 = fmaf(fmaxf(u0, 0.2f * u0), sa[i], p0);
            p1 = fmaf(fmaxf(u1, 0.2f * u1), sa[i], p1);
        }
        #pragma unroll
        for (int off = GS / 2; off >= 1; off >>= 1) {
            p0 += __shfl_xor(p0, off);
            p1 += __shfl_xor(p1, off);
        }
        if (j + 1 > e1) p1 = -INFINITY;   // odd tail: w1 = 0
        float hi = fmaxf(p0, p1);
        if (__all(hi <= m + 8.f)) {        // defer-max common path
            float w0 = __expf(p0 - m), w1 = __expf(p1 - m);
            l += w0 + w1;
            #pragma unroll
            for (int i = 0; i < CPL; i++)
                acc[i] = fmaf(w0, xl0[i], fmaf(w1, xl1[i], acc[i]));
        } else {                           // rescale path (first iter + rare)
            float mn = fmaxf(m, hi);
            float sc = __expf(m - mn);
            float w0 = __expf(p0 - mn), w1 = __expf(p1 - mn);
            l = fmaf(l, sc, w0 + w1);
            #pragma unroll
            for (int i = 0; i < CPL; i++)
                acc[i] = fmaf(acc[i], sc, fmaf(w0, xl0[i], w1 * xl1[i]));
            m = mn;
        }
        mdA = mdA_n; mdB = mdB_n; rA = rA_n; rB = rB_n;
    }

    float inv = 1.f / (l + 1e-16f);
    float o[CPL];
    float s = 0.f, s2 = 0.f;
    #pragma unroll
    for (int i = 0; i < CPL; i++) {
        o[i] = acc[i] * inv + bo[cb + i];
        s += o[i]; s2 += o[i] * o[i];
    }
    if constexpr (F32OUT) {
        float* q = outf + (size_t)n * HC + cb;
        if constexpr (CPL == 8) {
            *reinterpret_cast<float4*>(q)     = make_float4(o[0], o[1], o[2], o[3]);
            *reinterpret_cast<float4*>(q + 4) = make_float4(o[4], o[5], o[6], o[7]);
        } else if constexpr (CPL == 4) {
            *reinterpret_cast<float4*>(q) = make_float4(o[0], o[1], o[2], o[3]);
        } else {
            *reinterpret_cast<float2*>(q) = make_float2(o[0], o[1]);
        }
    } else {
        u16* q = outb + (size_t)n * HC + cb;
        if constexpr (CPL == 8) {
            *reinterpret_cast<uint4*>(q) =
                make_uint4(pack2(o[0], o[1]), pack2(o[2], o[3]),
                           pack2(o[4], o[5]), pack2(o[6], o[7]));
        } else if constexpr (CPL == 4) {
            *reinterpret_cast<uint2*>(q) =
                make_uint2(pack2(o[0], o[1]), pack2(o[2], o[3]));
        } else {
            *reinterpret_cast<unsigned*>(q) = pack2(o[0], o[1]);
        }
    }
    #pragma unroll
    for (int off = 32; off; off >>= 1) {
        s += __shfl_xor(s, off);
        s2 += __shfl_xor(s2, off);
    }
    if (lane == 0) {
        double* bk = sbuck + (size_t)(blockIdx.x & 511) * 2;
        atomicAdd(bk, (double)s);
        atomicAdd(bk + 1, (double)s2);
    }
}

// ---------------------------------------------------------------- pooling: fused LN finalize + LN+ELU + goff search

__global__ __launch_bounds__(256) void pool_ln(const float* __restrict__ h,
                                               const int* __restrict__ batch,
                                               const double* __restrict__ buck,
                                               double count,
                                               const float* __restrict__ lw,
                                               const float* __restrict__ lb,
                                               float* __restrict__ out, int N) {
    float2 lp = reduce_buckets(buck, count);
    __shared__ float sh[128], mh[128];
    int g = blockIdx.x;
    int s_ = 0, hi_ = N;
    while (s_ < hi_) { int mid = (s_ + hi_) >> 1; if (batch[mid] < g) s_ = mid + 1; else hi_ = mid; }
    int e_ = s_, hi2 = N;
    while (e_ < hi2) { int mid = (e_ + hi2) >> 1; if (batch[mid] < g + 1) e_ = mid + 1; else hi2 = mid; }
    int tid = threadIdx.x;
    int c = tid & 127, part = tid >> 7;
    float wc = lw[c] * lp.y, bc = lb[c];
    float sum = 0.f, mx = -INFINITY;
    for (int n = s_ + part; n < e_; n += 2) {
        float v = elu_fast((h[(size_t)n * 128 + c] - lp.x) * wc + bc);
        sum += v;
        mx = fmaxf(mx, v);
    }
    if (part == 1) { sh[c] = sum; mh[c] = mx; }
    __syncthreads();
    if (part == 0) {
        if (e_ - s_ > 1) { sum += sh[c]; mx = fmaxf(mx, mh[c]); }
        int cnt = e_ - s_;
        out[g * 256 + c] = cnt > 0 ? sum / (float)cnt : 0.f;
        out[g * 256 + 128 + c] = cnt > 0 ? mx : 0.f;
    }
}

// ---------------------------------------------------------------- launch

extern "C" void kernel_launch(void* const* d_in, const int* in_sizes, int n_in,
                              void* d_out, int out_size, void* d_ws, size_t ws_size,
                              hipStream_t stream) {
    const int N = N_NODES, E = N_EDGES, G = N_GRAPHS, E2 = E2_TOTAL;
    const float* x = (const float*)d_in[0];
    const int* ei = (const int*)d_in[1];
    const float* eattr = (const float*)d_in[2];
    const int* batch = (const int*)d_in[3];
    auto P = [&](int l, int k) { return (const float*)d_in[4 + l * 9 + k]; };
    // k: 0=Wl 1=bl 2=Wr 3=br 4=We 5=att 6=bo 7=lnw 8=lnb

    char* w = (char*)d_ws;
    size_t off = 0;
    auto alloc = [&](size_t bytes) -> void* {
        void* p = w + off;
        off += (bytes + 255) & ~(size_t)255;
        return p;
    };
    u16* Xa = (u16*)alloc((size_t)N * 512 * 2);      // XL per layer
    u16* Xb = (u16*)alloc((size_t)N * 512 * 2);      // XR per layer
    u16* Xc = (u16*)alloc((size_t)N * 512 * 2);      // raw attn out per layer
    float* H3f = (float*)alloc((size_t)N * 128 * 4); // layer-3 attn out fp32
    float4* meta = (float4*)alloc((size_t)E2 * 16);  // CSR-ordered {ea, src}
    u16* WtL = (u16*)alloc((size_t)512 * 256 * 2);
    u16* WtR = (u16*)alloc((size_t)512 * 256 * 2);
    int* rowptr = (int*)alloc((size_t)(N + 1) * 4);
    int* cursor = (int*)alloc((size_t)N * 4);
    // zero-initialized region: [zs, ze)
    size_t zs = off;
    int* deg = (int*)alloc((size_t)N * 4);
    float* asum = (float*)alloc((size_t)N * 3 * 4);
    double* b1 = (double*)alloc(512 * 2 * 8);
    double* b2 = (double*)alloc(512 * 2 * 8);
    double* b3 = (double*)alloc(512 * 2 * 8);
    size_t ze = off;
    (void)ws_size; (void)n_in; (void)in_sizes; (void)out_size;

    hipMemsetAsync(w + zs, 0, ze - zs, stream);

    deg_kernel<<<(E + 255) / 256, 256, 0, stream>>>(ei, eattr, deg, asum, E);
    scan_kernel<<<1, 1024, 0, stream>>>(deg, rowptr, cursor, N);
    fill_kernel<<<(E2 + 255) / 256, 256, 0, stream>>>(ei, eattr, asum, deg, cursor,
                                                      meta, E, E2);

    // -------- layer 1 (din=8, H=4, HC=512): SPLIT=1, CPL=8
    xw8_dual<<<(N + 63) / 64, 256, 0, stream>>>(x, P(0, 0), P(0, 1), P(0, 2), P(0, 3),
                                                Xa, Xb, N);
    attn_wave<512, 1, false><<<(N + 3) / 4, 256, 0, stream>>>(
        rowptr, meta, Xa, Xb, P(0, 4), P(0, 5), P(0, 6), nullptr, Xc, b1, N);

    // -------- layer 2 (din=512, H=2, HC=256); LN+ELU fused into gemm A-path
    {
        dim3 tg(512 / 64, 256 / 64, 2);
        wt_dual<<<tg, 256, 0, stream>>>(P(1, 0), P(1, 2), WtL, WtR, 512, 256);
        dim3 gg((N + 127) / 128, 2, 2);
        gemm_dual<<<gg, 256, 0, stream>>>(Xc, WtL, WtR, P(1, 1), P(1, 3),
                                          Xa, Xb, b1, (double)N * 512.0,
                                          P(0, 7), P(0, 8), N, 512, 256);
    }
    attn_wave<256, 1, false><<<(N + 3) / 4, 256, 0, stream>>>(
        rowptr, meta, Xa, Xb, P(1, 4), P(1, 5), P(1, 6), nullptr, Xc, b2, N);

    // -------- layer 3 (din=256, H=1, HC=128); LN+ELU fused into gemm A-path
    {
        dim3 tg(256 / 64, 128 / 64, 2);
        wt_dual<<<tg, 256, 0, stream>>>(P(2, 0), P(2, 2), WtL, WtR, 256, 128);
        dim3 gg((N + 127) / 128, 1, 2);
        gemm_dual<<<gg, 256, 0, stream>>>(Xc, WtL, WtR, P(2, 1), P(2, 3),
                                          Xa, Xb, b2, (double)N * 256.0,
                                          P(1, 7), P(1, 8), N, 256, 128);
    }
    attn_wave<128, 1, true><<<(N + 3) / 4, 256, 0, stream>>>(
        rowptr, meta, Xa, Xb, P(2, 4), P(2, 5), P(2, 6), H3f, nullptr, b3, N);

    // -------- pooling (fused LN finalize + apply + goff search)
    pool_ln<<<G, 256, 0, stream>>>(H3f, batch, b3, (double)N * 128.0,
                                   P(2, 7), P(2, 8), (float*)d_out, N);
}